// Round 16
// baseline (1248.629 us; speedup 1.0000x reference)
//
#include <hip/hip_runtime.h>
#include <math.h>

#define NBOX 1000
#define NIMG 2
#define CCH 256
#define FCIN 12544   // 256*7*7
#define FCD 1024
#define TOPK 100
#define SCALE_CLAMP_F ((float)4.135166556742356)  // f32(np.log(1000/16))
#define KC 384       // OpenBLAS SGEMM_DEFAULT_Q -- FROZEN numerics invariant
#define NPANEL 33    // 12544 = 32*384 + 256
#define RB 16        // rows per fc1 panel-block
#define NGROUP 125   // 2000/16
#define CHUNK 128    // LDS staging chunk (divides 384 and 256)
#define RB2 8        // rows per fc2 panel-block
#define NP2 3        // fc2 panels: 384,384,256
#define R1 8         // rows per block, fallback path

// ---------------- Prep: per-box level + gather indices (strict f32, numpy op order) ----------------
__global__ void prep_kernel(const float* __restrict__ props, int* __restrict__ prep) {
    int b = blockIdx.x * blockDim.x + threadIdx.x;
    if (b >= NIMG * NBOX) return;
    int n = b / NBOX;
    const float* pr = props + (size_t)b * 4;
    float x1 = pr[0], y1 = pr[1], x2 = pr[2], y2 = pr[3];

    float w = __fsub_rn(x2, x1), h = __fsub_rn(y2, y1);
    float s = sqrtf(fmaxf(__fmul_rn(w, h), 1e-6f));
    float l2 = (float)log2((double)__fadd_rn(__fdiv_rn(s, 224.0f), 1e-8f));
    float lv = floorf(__fadd_rn(4.0f, l2));
    lv = fminf(fmaxf(lv, 2.0f), 5.0f);
    int lvl = (int)lv - 2;

    int H, W; float scale;
    if (lvl == 0)      { H = 200; W = 304; scale = 0.25f; }
    else if (lvl == 1) { H = 100; W = 152; scale = 0.125f; }
    else if (lvl == 2) { H = 50;  W = 76;  scale = 0.0625f; }
    else               { H = 25;  W = 38;  scale = 0.03125f; }

    float xs1 = __fmul_rn(x1, scale), ys1 = __fmul_rn(y1, scale);
    float xs2 = __fmul_rn(x2, scale), ys2 = __fmul_rn(y2, scale);
    float bw = __fdiv_rn(fmaxf(__fsub_rn(xs2, xs1), 1.0f), 7.0f);
    float bh = __fdiv_rn(fmaxf(__fsub_rn(ys2, ys1), 1.0f), 7.0f);

    int* pb = prep + b * 20;
    pb[0] = lvl;
    pb[1] = n * CCH * H * W;
    pb[2] = H * W;
#pragma unroll
    for (int i = 0; i < 7; i++) {
        float cs = (float)i + 0.5f;
        float gx = __fadd_rn(xs1, __fmul_rn(cs, bw));
        float gy = __fadd_rn(ys1, __fmul_rn(cs, bh));
        int vx = (int)gx;
        int vy = (int)gy;
        vx = vx < 0 ? 0 : (vx > W - 1 ? W - 1 : vx);
        vy = vy < 0 ? 0 : (vy > H - 1 ? H - 1 : vy);
        pb[4 + i] = vx;
        pb[12 + i] = vy * W;
    }
}

// ================= Panel-parallel FC1: 8 rows x 8 cols per thread =================
// Block = one panel p x 16 rows x 1024 cols. 256 thr = 2 row-halves x 128 col-threads.
// Per k: 2 ds_read_b128 (broadcast) + 2 global dwordx4 -> 64 FMA. LDS/FMA halved vs r13.
// Per-output ascending-k fma chain preserved exactly.
#define FR8(AX, RI)                                       \
    acc[RI][0] = fmaf(AX, W0.x, acc[RI][0]);              \
    acc[RI][1] = fmaf(AX, W0.y, acc[RI][1]);              \
    acc[RI][2] = fmaf(AX, W0.z, acc[RI][2]);              \
    acc[RI][3] = fmaf(AX, W0.w, acc[RI][3]);              \
    acc[RI][4] = fmaf(AX, W1.x, acc[RI][4]);              \
    acc[RI][5] = fmaf(AX, W1.y, acc[RI][5]);              \
    acc[RI][6] = fmaf(AX, W1.z, acc[RI][6]);              \
    acc[RI][7] = fmaf(AX, W1.w, acc[RI][7]);

#define FMASTEP8(KB, WV0, WV1)                                        \
    {                                                                 \
        const float4* xv = (const float4*)&xs[(KB)][half8];           \
        float4 a0 = xv[0], a1 = xv[1];                                \
        float4 W0 = WV0, W1 = WV1;                                    \
        FR8(a0.x, 0) FR8(a0.y, 1) FR8(a0.z, 2) FR8(a0.w, 3)           \
        FR8(a1.x, 4) FR8(a1.y, 5) FR8(a1.z, 6) FR8(a1.w, 7)           \
    }

__global__ __launch_bounds__(256, 4) void fc1_panel(
    const float* __restrict__ p2, const float* __restrict__ p3,
    const float* __restrict__ p4, const float* __restrict__ p5,
    const int* __restrict__ prep, const float* __restrict__ W1,
    float* __restrict__ part, int g0, int gs) {
    __shared__ float xs[CHUNK][RB];
    __shared__ int s_ix[RB][7], s_iyW[RB][7], s_HW[RB];
    __shared__ const float* s_fp[RB];

    int tid = threadIdx.x;
    int half = tid >> 7;                 // row half: rows half*8 .. half*8+7
    int half8 = half * 8;
    int ct = tid & 127;                  // col-thread
    int col0 = ct * 8;
    int gy = blockIdx.x;
    int p = blockIdx.y;
    int row0 = (g0 + gy) * RB;
    int k0 = p * KC;
    int kt = (p == NPANEL - 1) ? 256 : KC;

    if (tid < RB) {
        const int* pb = prep + (row0 + tid) * 20;
        int lvl = pb[0];
        s_fp[tid] = (lvl == 0 ? p2 : lvl == 1 ? p3 : lvl == 2 ? p4 : p5) + pb[1];
        s_HW[tid] = pb[2];
#pragma unroll
        for (int j = 0; j < 7; j++) { s_ix[tid][j] = pb[4 + j]; s_iyW[tid][j] = pb[12 + j]; }
    }
    __syncthreads();

    float acc[8][8];
#pragma unroll
    for (int r = 0; r < 8; r++)
#pragma unroll
        for (int j = 0; j < 8; j++) acc[r][j] = 0.0f;

    const float* wp = W1 + (size_t)k0 * FCD + col0;

    for (int ck = 0; ck < kt; ck += CHUNK) {
        for (int e = tid; e < CHUNK * RB; e += 256) {
            int kk = e >> 4;
            int r = e & 15;
            int k = k0 + ck + kk;
            int c = k / 49;
            int pp = k - c * 49;
            int gyy = pp / 7;
            int gxx = pp - gyy * 7;
            xs[kk][r] = s_fp[r][c * s_HW[r] + s_iyW[r][gyy] + s_ix[r][gxx]];
        }
        __syncthreads();

        const float* wc = wp + (size_t)ck * FCD;
        float4 wA0 = *(const float4*)(wc);
        float4 wA1 = *(const float4*)(wc + 4);
        for (int kk = 0; kk < CHUNK; kk += 2) {
            float4 wB0 = *(const float4*)(wc + (size_t)(kk + 1) * FCD);
            float4 wB1 = *(const float4*)(wc + (size_t)(kk + 1) * FCD + 4);
            FMASTEP8(kk, wA0, wA1)               // k ascending: chain order preserved
            if (kk + 2 < CHUNK) {
                wA0 = *(const float4*)(wc + (size_t)(kk + 2) * FCD);
                wA1 = *(const float4*)(wc + (size_t)(kk + 2) * FCD + 4);
            }
            FMASTEP8(kk + 1, wB0, wB1)
        }
        __syncthreads();
    }

    size_t pstride = (size_t)gs * RB * FCD;
    float* po = part + (size_t)p * pstride + ((size_t)(gy * RB + half8)) * FCD + col0;
#pragma unroll
    for (int r = 0; r < 8; r++) {
        *(float4*)(po + (size_t)r * FCD)     = make_float4(acc[r][0], acc[r][1], acc[r][2], acc[r][3]);
        *(float4*)(po + (size_t)r * FCD + 4) = make_float4(acc[r][4], acc[r][5], acc[r][6], acc[r][7]);
    }
}

// ================= Panel-parallel FC2 (unchanged from round 15) =================
__global__ __launch_bounds__(256, 4) void fc2_panel(
    const float* __restrict__ X1, const float* __restrict__ W2,
    float* __restrict__ part) {
    __shared__ float xs2[CHUNK][RB2];
    int tid = threadIdx.x;
    int gy = blockIdx.x;
    int p = blockIdx.y;
    int row0 = gy * RB2;
    int k0 = p * KC;
    int kt = (p == NP2 - 1) ? 256 : KC;

    float acc[RB2][4];
#pragma unroll
    for (int r = 0; r < RB2; r++)
#pragma unroll
        for (int j = 0; j < 4; j++) acc[r][j] = 0.0f;

    const float* wp = W2 + (size_t)k0 * FCD + tid * 4;

    for (int ck = 0; ck < kt; ck += CHUNK) {
        for (int e = tid; e < CHUNK * RB2; e += 256) {
            int kk = e >> 3;
            int r = e & 7;
            xs2[kk][r] = X1[(size_t)(row0 + r) * FCD + k0 + ck + kk];
        }
        __syncthreads();

        const float* wc = wp + (size_t)ck * FCD;
        float4 wA = *(const float4*)wc;
        for (int kk = 0; kk < CHUNK; kk += 2) {
            float4 wB = *(const float4*)(wc + (size_t)(kk + 1) * FCD);
            {
                const float4* xv = (const float4*)&xs2[kk][0];
                float4 a0 = xv[0], a1 = xv[1];
                float4 WV = wA;
                acc[0][0] = fmaf(a0.x, WV.x, acc[0][0]); acc[0][1] = fmaf(a0.x, WV.y, acc[0][1]);
                acc[0][2] = fmaf(a0.x, WV.z, acc[0][2]); acc[0][3] = fmaf(a0.x, WV.w, acc[0][3]);
                acc[1][0] = fmaf(a0.y, WV.x, acc[1][0]); acc[1][1] = fmaf(a0.y, WV.y, acc[1][1]);
                acc[1][2] = fmaf(a0.y, WV.z, acc[1][2]); acc[1][3] = fmaf(a0.y, WV.w, acc[1][3]);
                acc[2][0] = fmaf(a0.z, WV.x, acc[2][0]); acc[2][1] = fmaf(a0.z, WV.y, acc[2][1]);
                acc[2][2] = fmaf(a0.z, WV.z, acc[2][2]); acc[2][3] = fmaf(a0.z, WV.w, acc[2][3]);
                acc[3][0] = fmaf(a0.w, WV.x, acc[3][0]); acc[3][1] = fmaf(a0.w, WV.y, acc[3][1]);
                acc[3][2] = fmaf(a0.w, WV.z, acc[3][2]); acc[3][3] = fmaf(a0.w, WV.w, acc[3][3]);
                acc[4][0] = fmaf(a1.x, WV.x, acc[4][0]); acc[4][1] = fmaf(a1.x, WV.y, acc[4][1]);
                acc[4][2] = fmaf(a1.x, WV.z, acc[4][2]); acc[4][3] = fmaf(a1.x, WV.w, acc[4][3]);
                acc[5][0] = fmaf(a1.y, WV.x, acc[5][0]); acc[5][1] = fmaf(a1.y, WV.y, acc[5][1]);
                acc[5][2] = fmaf(a1.y, WV.z, acc[5][2]); acc[5][3] = fmaf(a1.y, WV.w, acc[5][3]);
                acc[6][0] = fmaf(a1.z, WV.x, acc[6][0]); acc[6][1] = fmaf(a1.z, WV.y, acc[6][1]);
                acc[6][2] = fmaf(a1.z, WV.z, acc[6][2]); acc[6][3] = fmaf(a1.z, WV.w, acc[6][3]);
                acc[7][0] = fmaf(a1.w, WV.x, acc[7][0]); acc[7][1] = fmaf(a1.w, WV.y, acc[7][1]);
                acc[7][2] = fmaf(a1.w, WV.z, acc[7][2]); acc[7][3] = fmaf(a1.w, WV.w, acc[7][3]);
            }
            if (kk + 2 < CHUNK) wA = *(const float4*)(wc + (size_t)(kk + 2) * FCD);
            {
                const float4* xv = (const float4*)&xs2[kk + 1][0];
                float4 a0 = xv[0], a1 = xv[1];
                float4 WV = wB;
                acc[0][0] = fmaf(a0.x, WV.x, acc[0][0]); acc[0][1] = fmaf(a0.x, WV.y, acc[0][1]);
                acc[0][2] = fmaf(a0.x, WV.z, acc[0][2]); acc[0][3] = fmaf(a0.x, WV.w, acc[0][3]);
                acc[1][0] = fmaf(a0.y, WV.x, acc[1][0]); acc[1][1] = fmaf(a0.y, WV.y, acc[1][1]);
                acc[1][2] = fmaf(a0.y, WV.z, acc[1][2]); acc[1][3] = fmaf(a0.y, WV.w, acc[1][3]);
                acc[2][0] = fmaf(a0.z, WV.x, acc[2][0]); acc[2][1] = fmaf(a0.z, WV.y, acc[2][1]);
                acc[2][2] = fmaf(a0.z, WV.z, acc[2][2]); acc[2][3] = fmaf(a0.z, WV.w, acc[2][3]);
                acc[3][0] = fmaf(a0.w, WV.x, acc[3][0]); acc[3][1] = fmaf(a0.w, WV.y, acc[3][1]);
                acc[3][2] = fmaf(a0.w, WV.z, acc[3][2]); acc[3][3] = fmaf(a0.w, WV.w, acc[3][3]);
                acc[4][0] = fmaf(a1.x, WV.x, acc[4][0]); acc[4][1] = fmaf(a1.x, WV.y, acc[4][1]);
                acc[4][2] = fmaf(a1.x, WV.z, acc[4][2]); acc[4][3] = fmaf(a1.x, WV.w, acc[4][3]);
                acc[5][0] = fmaf(a1.y, WV.x, acc[5][0]); acc[5][1] = fmaf(a1.y, WV.y, acc[5][1]);
                acc[5][2] = fmaf(a1.y, WV.z, acc[5][2]); acc[5][3] = fmaf(a1.y, WV.w, acc[5][3]);
                acc[6][0] = fmaf(a1.z, WV.x, acc[6][0]); acc[6][1] = fmaf(a1.z, WV.y, acc[6][1]);
                acc[6][2] = fmaf(a1.z, WV.z, acc[6][2]); acc[6][3] = fmaf(a1.z, WV.w, acc[6][3]);
                acc[7][0] = fmaf(a1.w, WV.x, acc[7][0]); acc[7][1] = fmaf(a1.w, WV.y, acc[7][1]);
                acc[7][2] = fmaf(a1.w, WV.z, acc[7][2]); acc[7][3] = fmaf(a1.w, WV.w, acc[7][3]);
            }
        }
        __syncthreads();
    }

    size_t pstride = (size_t)NIMG * NBOX * FCD;
    float* po = part + (size_t)p * pstride + ((size_t)row0) * FCD + tid * 4;
#pragma unroll
    for (int r = 0; r < RB2; r++) {
        float4 v = make_float4(acc[r][0], acc[r][1], acc[r][2], acc[r][3]);
        *(float4*)(po + (size_t)r * FCD) = v;
    }
}

// Ordered left-fold over panel chains + bias + ReLU. Exact OpenBLAS panel fold.
__global__ void fold_bias_relu(const float* __restrict__ part, const float* __restrict__ bias,
                               float* __restrict__ Xout, int row_base, int rows_s, int npanel) {
    int idx = blockIdx.x * 256 + threadIdx.x;
    if (idx >= rows_s * FCD) return;
    size_t stride = (size_t)rows_s * FCD;
    float tot = part[idx];
    for (int p = 1; p < npanel; p++)
        tot = __fadd_rn(tot, part[(size_t)p * stride + idx]);
    int c = idx & (FCD - 1);
    float v = __fadd_rn(tot, bias[c]);
    Xout[(size_t)row_base * FCD + idx] = fmaxf(v, 0.0f);
}

// ================= fallback machinery (round-10, proven bit-exact) =================
#define FMA8(BUF, KB)                                                                   \
    _Pragma("unroll")                                                                   \
    for (int u = 0; u < 8; u++) {                                                       \
        const float4* xv = (const float4*)&xs[(KB) + u][0];                             \
        float4 a0 = xv[0], a1 = xv[1];                                                  \
        float wx = BUF[u].x, wy = BUF[u].y;                                             \
        acc[0][0] = fmaf(a0.x, wx, acc[0][0]); acc[0][1] = fmaf(a0.x, wy, acc[0][1]);   \
        acc[1][0] = fmaf(a0.y, wx, acc[1][0]); acc[1][1] = fmaf(a0.y, wy, acc[1][1]);   \
        acc[2][0] = fmaf(a0.z, wx, acc[2][0]); acc[2][1] = fmaf(a0.z, wy, acc[2][1]);   \
        acc[3][0] = fmaf(a0.w, wx, acc[3][0]); acc[3][1] = fmaf(a0.w, wy, acc[3][1]);   \
        acc[4][0] = fmaf(a1.x, wx, acc[4][0]); acc[4][1] = fmaf(a1.x, wy, acc[4][1]);   \
        acc[5][0] = fmaf(a1.y, wx, acc[5][0]); acc[5][1] = fmaf(a1.y, wy, acc[5][1]);   \
        acc[6][0] = fmaf(a1.z, wx, acc[6][0]); acc[6][1] = fmaf(a1.z, wy, acc[6][1]);   \
        acc[7][0] = fmaf(a1.w, wx, acc[7][0]); acc[7][1] = fmaf(a1.w, wy, acc[7][1]);   \
    }

template <int KT>
__device__ __forceinline__ void fc_panel2(const float* __restrict__ wp,
                                          const float (*xs)[R1],
                                          float acc[R1][2]) {
    float2 wa[8], wb[8];
#pragma unroll
    for (int u = 0; u < 8; u++) wa[u] = *(const float2*)(wp + (size_t)u * FCD);
    for (int kk = 0; kk < KT; kk += 16) {
#pragma unroll
        for (int u = 0; u < 8; u++)
            wb[u] = *(const float2*)(wp + (size_t)(kk + 8 + u) * FCD);
        FMA8(wa, kk)
        if (kk + 16 < KT) {
#pragma unroll
            for (int u = 0; u < 8; u++)
                wa[u] = *(const float2*)(wp + (size_t)(kk + 16 + u) * FCD);
        }
        FMA8(wb, kk + 8)
    }
}

__global__ __launch_bounds__(256) void fc1_fallback(
    const float* __restrict__ p2, const float* __restrict__ p3,
    const float* __restrict__ p4, const float* __restrict__ p5,
    const int* __restrict__ prep, const float* __restrict__ W1,
    const float* __restrict__ b1, float* __restrict__ X1) {
    __shared__ float xs[KC][R1];
    __shared__ int s_ix[R1][7], s_iyW[R1][7], s_HW[R1];
    __shared__ const float* s_fp[R1];

    int tid = threadIdx.x;
    int c0 = blockIdx.x * 512 + tid * 2;
    int row0 = blockIdx.y * R1;

    if (tid < R1) {
        const int* pb = prep + (row0 + tid) * 20;
        int lvl = pb[0];
        s_fp[tid] = (lvl == 0 ? p2 : lvl == 1 ? p3 : lvl == 2 ? p4 : p5) + pb[1];
        s_HW[tid] = pb[2];
#pragma unroll
        for (int j = 0; j < 7; j++) { s_ix[tid][j] = pb[4 + j]; s_iyW[tid][j] = pb[12 + j]; }
    }

    float tot[R1][2];
#pragma unroll
    for (int r = 0; r < R1; r++) { tot[r][0] = 0.0f; tot[r][1] = 0.0f; }

    for (int k0 = 0; k0 < FCIN; k0 += KC) {
        int kt = FCIN - k0; if (kt > KC) kt = KC;
        __syncthreads();
        for (int e = tid; e < kt * R1; e += 256) {
            int kk = e >> 3;
            int r = e & 7;
            int k = k0 + kk;
            int c = k / 49;
            int p = k - c * 49;
            int gy = p / 7;
            int gx = p - gy * 7;
            xs[kk][r] = s_fp[r][c * s_HW[r] + s_iyW[r][gy] + s_ix[r][gx]];
        }
        __syncthreads();

        float acc[R1][2];
#pragma unroll
        for (int r = 0; r < R1; r++) { acc[r][0] = 0.0f; acc[r][1] = 0.0f; }

        const float* wp = W1 + (size_t)k0 * FCD + c0;
        if (kt == KC) fc_panel2<KC>(wp, xs, acc);
        else          fc_panel2<256>(wp, xs, acc);

#pragma unroll
        for (int r = 0; r < R1; r++) {
            tot[r][0] = __fadd_rn(tot[r][0], acc[r][0]);
            tot[r][1] = __fadd_rn(tot[r][1], acc[r][1]);
        }
    }
    float bv0 = b1[c0], bv1 = b1[c0 + 1];
#pragma unroll
    for (int r = 0; r < R1; r++) {
        float v0 = __fadd_rn(tot[r][0], bv0);
        float v1 = __fadd_rn(tot[r][1], bv1);
        X1[(size_t)(row0 + r) * FCD + c0]     = fmaxf(v0, 0.0f);
        X1[(size_t)(row0 + r) * FCD + c0 + 1] = fmaxf(v1, 0.0f);
    }
}

__global__ __launch_bounds__(256) void fc2_seq(
    const float* __restrict__ X1, const float* __restrict__ W2,
    const float* __restrict__ b2, float* __restrict__ X2) {
    __shared__ float xs[KC][R1];
    int tid = threadIdx.x;
    int c0 = blockIdx.x * 512 + tid * 2;
    int row0 = blockIdx.y * R1;

    float tot[R1][2];
#pragma unroll
    for (int r = 0; r < R1; r++) { tot[r][0] = 0.0f; tot[r][1] = 0.0f; }

    for (int k0 = 0; k0 < FCD; k0 += KC) {
        int kt = FCD - k0; if (kt > KC) kt = KC;
        __syncthreads();
        for (int e = tid; e < kt * R1; e += 256) {
            int kk = e >> 3;
            int r = e & 7;
            xs[kk][r] = X1[(size_t)(row0 + r) * FCD + k0 + kk];
        }
        __syncthreads();

        float acc[R1][2];
#pragma unroll
        for (int r = 0; r < R1; r++) { acc[r][0] = 0.0f; acc[r][1] = 0.0f; }

        const float* wp = W2 + (size_t)k0 * FCD + c0;
        if (kt == KC) fc_panel2<KC>(wp, xs, acc);
        else          fc_panel2<256>(wp, xs, acc);

#pragma unroll
        for (int r = 0; r < R1; r++) {
            tot[r][0] = __fadd_rn(tot[r][0], acc[r][0]);
            tot[r][1] = __fadd_rn(tot[r][1], acc[r][1]);
        }
    }
    float bv0 = b2[c0], bv1 = b2[c0 + 1];
#pragma unroll
    for (int r = 0; r < R1; r++) {
        float v0 = __fadd_rn(tot[r][0], bv0);
        float v1 = __fadd_rn(tot[r][1], bv1);
        X2[(size_t)(row0 + r) * FCD + c0]     = fmaxf(v0, 0.0f);
        X2[(size_t)(row0 + r) * FCD + c0 + 1] = fmaxf(v1, 0.0f);
    }
}

// ---------------- Heads: 6 sgemm-order dots (KC panels), softmax, decode, clip ----------------
__global__ __launch_bounds__(256) void heads_seq(
    const float* __restrict__ X2,
    const float* __restrict__ Wc, const float* __restrict__ bc,
    const float* __restrict__ Wb, const float* __restrict__ bb_,
    const float* __restrict__ props, const int* __restrict__ img_sz,
    float* __restrict__ SC, float* __restrict__ BX) {
    int b = blockIdx.x;
    int tid = threadIdx.x;
    __shared__ float xsh[FCD];
    __shared__ float lg[6];
    for (int k = tid; k < FCD; k += 256) xsh[k] = X2[(size_t)b * FCD + k];
    __syncthreads();

    if (tid < 6) {
        const float* wp; int st; float bias;
        if (tid < 2) { wp = Wc + tid; st = 2; bias = bc[tid]; }
        else         { wp = Wb + (tid - 2); st = 4; bias = bb_[tid - 2]; }
        float tot = 0.0f;
        for (int k0 = 0; k0 < FCD; k0 += KC) {
            int kt = FCD - k0; if (kt > KC) kt = KC;
            float acc = 0.0f;
            for (int k = k0; k < k0 + kt; k++) acc = fmaf(xsh[k], wp[(size_t)k * st], acc);
            tot = __fadd_rn(tot, acc);
        }
        lg[tid] = __fadd_rn(tot, bias);
    }
    __syncthreads();

    if (tid == 0) {
        float c0 = lg[0], c1 = lg[1];
        float mx = fmaxf(c0, c1);
        float e0 = (float)exp((double)__fsub_rn(c0, mx));
        float e1 = (float)exp((double)__fsub_rn(c1, mx));
        SC[b] = __fdiv_rn(e1, __fadd_rn(e0, e1));

        int n = b / NBOX;
        const float* pr = props + (size_t)b * 4;
        float x1 = pr[0], y1 = pr[1], x2 = pr[2], y2 = pr[3];
        float w = __fsub_rn(x2, x1), h = __fsub_rn(y2, y1);
        float cx = __fadd_rn(x1, __fmul_rn(0.5f, w));
        float cy = __fadd_rn(y1, __fmul_rn(0.5f, h));
        float dx = lg[2], dy = lg[3];
        float dw = fminf(lg[4], SCALE_CLAMP_F);
        float dh = fminf(lg[5], SCALE_CLAMP_F);
        float pcx = __fadd_rn(__fmul_rn(dx, w), cx);
        float pcy = __fadd_rn(__fmul_rn(dy, h), cy);
        float pw = __fmul_rn((float)exp((double)dw), w);
        float ph = __fmul_rn((float)exp((double)dh), h);
        float bx1 = __fsub_rn(pcx, __fmul_rn(0.5f, pw));
        float by1 = __fsub_rn(pcy, __fmul_rn(0.5f, ph));
        float bx2 = __fadd_rn(pcx, __fmul_rn(0.5f, pw));
        float by2 = __fadd_rn(pcy, __fmul_rn(0.5f, ph));
        float Hf = (float)img_sz[n * 2 + 0], Wf = (float)img_sz[n * 2 + 1];
        bx1 = fminf(fmaxf(bx1, 0.0f), Wf);
        by1 = fminf(fmaxf(by1, 0.0f), Hf);
        bx2 = fminf(fmaxf(bx2, 0.0f), Wf);
        by2 = fminf(fmaxf(by2, 0.0f), Hf);
        BX[(size_t)b * 4 + 0] = bx1;
        BX[(size_t)b * 4 + 1] = by1;
        BX[(size_t)b * 4 + 2] = bx2;
        BX[(size_t)b * 4 + 3] = by2;
    }
}

// ---------------- Sort + NMS + topk (strict f32, numpy op order) ----------------
__global__ __launch_bounds__(1024) void nms_kernel(const float* __restrict__ SC,
                                                   const float* __restrict__ BX,
                                                   float* __restrict__ out) {
    int n = blockIdx.x;
    __shared__ float sraw[NBOX];
    __shared__ float ssort[NBOX];
    __shared__ float bsort[NBOX][4];
    __shared__ int ord[NBOX];
    __shared__ unsigned char keep[NBOX];
    int tid = threadIdx.x;

    for (int j = tid; j < NBOX; j += 1024) sraw[j] = SC[n * NBOX + j];
    __syncthreads();

    if (tid < NBOX) {
        float sj = sraw[tid];
        int r = 0;
        for (int k = 0; k < NBOX; k++) {
            float sk = sraw[k];
            r += (sk > sj) || (sk == sj && k < tid);
        }
        ord[r] = tid;
        ssort[r] = sj;
#pragma unroll
        for (int k = 0; k < 4; k++) bsort[r][k] = BX[((size_t)n * NBOX + tid) * 4 + k];
        keep[r] = (sj > 0.05f) ? 1 : 0;
    }
    __syncthreads();

    for (int i = 0; i < NBOX - 1; i++) {
        if (keep[i] && tid > i && tid < NBOX && keep[tid]) {
            float ax1 = bsort[i][0], ay1 = bsort[i][1], ax2 = bsort[i][2], ay2 = bsort[i][3];
            float bx1 = bsort[tid][0], by1 = bsort[tid][1], bx2 = bsort[tid][2], by2 = bsort[tid][3];
            float areaA = __fmul_rn(__fsub_rn(ax2, ax1), __fsub_rn(ay2, ay1));
            float areaB = __fmul_rn(__fsub_rn(bx2, bx1), __fsub_rn(by2, by1));
            float ix1 = fmaxf(ax1, bx1), iy1 = fmaxf(ay1, by1);
            float ix2 = fminf(ax2, bx2), iy2 = fminf(ay2, by2);
            float iw = fmaxf(__fsub_rn(ix2, ix1), 0.0f);
            float ih = fmaxf(__fsub_rn(iy2, iy1), 0.0f);
            float inter = __fmul_rn(iw, ih);
            float denom = fmaxf(__fsub_rn(__fadd_rn(areaA, areaB), inter), 1e-9f);
            if (__fdiv_rn(inter, denom) > 0.5f) keep[tid] = 0;
        }
        __syncthreads();
    }

    if (tid == 0) {
        int c = 0;
        for (int r = 0; r < NBOX; r++) {
            int k = keep[r];
            c += k;
            keep[r] = (k && (c <= TOPK)) ? 1 : 0;
        }
    }
    __syncthreads();

    float* boxes_o = out;
    float* scores_o = out + (size_t)NIMG * NBOX * 4;
    float* keep_o = scores_o + (size_t)NIMG * NBOX;
    float* ord_o = keep_o + (size_t)NIMG * NBOX;
    for (int r = tid; r < NBOX; r += 1024) {
#pragma unroll
        for (int k = 0; k < 4; k++)
            boxes_o[((size_t)n * NBOX + r) * 4 + k] = bsort[r][k];
        scores_o[n * NBOX + r] = ssort[r];
        keep_o[n * NBOX + r] = (float)keep[r];
        ord_o[n * NBOX + r] = (float)ord[r];
    }
}

extern "C" void kernel_launch(void* const* d_in, const int* in_sizes, int n_in,
                              void* d_out, int out_size, void* d_ws, size_t ws_size,
                              hipStream_t stream) {
    const float* p2 = (const float*)d_in[0];
    const float* p3 = (const float*)d_in[1];
    const float* p4 = (const float*)d_in[2];
    const float* p5 = (const float*)d_in[3];
    const float* props = (const float*)d_in[4];
    const int* img = (const int*)d_in[5];
    const float* W1 = (const float*)d_in[6];
    const float* b1 = (const float*)d_in[7];
    const float* W2 = (const float*)d_in[8];
    const float* b2 = (const float*)d_in[9];
    const float* Wc = (const float*)d_in[10];
    const float* bc = (const float*)d_in[11];
    const float* Wb = (const float*)d_in[12];
    const float* bb = (const float*)d_in[13];

    float* X1 = (float*)d_ws;
    float* X2 = X1 + (size_t)2000 * FCD;
    float* SCf = X2 + (size_t)2000 * FCD;
    float* BXf = SCf + 2000;
    int* prep = (int*)(BXf + 8000);
    float* part = (float*)(prep + 2000 * 20);
    size_t used = (size_t)((char*)part - (char*)d_ws);
    size_t avail = ws_size > used ? ws_size - used : 0;

    prep_kernel<<<(NIMG * NBOX + 255) / 256, 256, 0, stream>>>(props, prep);

    // fc1: prefer single sweep (round-13/15 proven optimum)
    int gmax = 0;
    const int cand[4] = {125, 63, 32, 16};
    for (int i = 0; i < 4; i++) {
        size_t need = (size_t)NPANEL * cand[i] * RB * FCD * sizeof(float);
        if (need <= avail) { gmax = cand[i]; break; }
    }

    if (gmax > 0) {
        for (int g0 = 0; g0 < NGROUP; g0 += gmax) {
            int gs = NGROUP - g0; if (gs > gmax) gs = gmax;
            dim3 gA(gs, NPANEL);
            fc1_panel<<<gA, 256, 0, stream>>>(p2, p3, p4, p5, prep, W1, part, g0, gs);
            int nelem = gs * RB * FCD;
            fold_bias_relu<<<(nelem + 255) / 256, 256, 0, stream>>>(part, b1, X1,
                                                                    g0 * RB, gs * RB, NPANEL);
        }
    } else {
        dim3 gfc(2, (NIMG * NBOX) / R1);
        fc1_fallback<<<gfc, 256, 0, stream>>>(p2, p3, p4, p5, prep, W1, b1, X1);
    }

    // fc2: panel-parallel if partial buffer fits (24.6 MB), else proven fc2_seq
    size_t need2 = (size_t)NP2 * NIMG * NBOX * FCD * sizeof(float);
    if (need2 <= avail) {
        dim3 g2(NIMG * NBOX / RB2, NP2);           // (250, 3)
        fc2_panel<<<g2, 256, 0, stream>>>(X1, W2, part);
        int nelem2 = NIMG * NBOX * FCD;
        fold_bias_relu<<<(nelem2 + 255) / 256, 256, 0, stream>>>(part, b2, X2,
                                                                 0, NIMG * NBOX, NP2);
    } else {
        dim3 gfc2(2, (NIMG * NBOX) / R1);
        fc2_seq<<<gfc2, 256, 0, stream>>>(X1, W2, b2, X2);
    }

    heads_seq<<<NIMG * NBOX, 256, 0, stream>>>(X2, Wc, bc, Wb, bb, props, img, SCf, BXf);

    nms_kernel<<<NIMG, 1024, 0, stream>>>(SCf, BXf, (float*)d_out);
}

// Round 17
// 1162.240 us; speedup vs baseline: 1.0743x; 1.0743x over previous
//
#include <hip/hip_runtime.h>
#include <math.h>

#define NBOX 1000
#define NIMG 2
#define CCH 256
#define FCIN 12544   // 256*7*7
#define FCD 1024
#define TOPK 100
#define SCALE_CLAMP_F ((float)4.135166556742356)  // f32(np.log(1000/16))
#define KC 384       // OpenBLAS SGEMM_DEFAULT_Q -- FROZEN numerics invariant
#define NPANEL 33    // 12544 = 32*384 + 256
#define RB 16        // rows per fc1 panel-block
#define NGROUP 125   // 2000/16
#define CHUNK 128    // LDS staging chunk (divides 384 and 256)
#define RB2 8        // rows per fc2 panel-block
#define NP2 3        // fc2 panels: 384,384,256
#define R1 8         // rows per block, fallback path
#define HB 8         // boxes per heads block

// ---------------- Prep: per-box level + gather indices (strict f32, numpy op order) ----------------
__global__ void prep_kernel(const float* __restrict__ props, int* __restrict__ prep) {
    int b = blockIdx.x * blockDim.x + threadIdx.x;
    if (b >= NIMG * NBOX) return;
    int n = b / NBOX;
    const float* pr = props + (size_t)b * 4;
    float x1 = pr[0], y1 = pr[1], x2 = pr[2], y2 = pr[3];

    float w = __fsub_rn(x2, x1), h = __fsub_rn(y2, y1);
    float s = sqrtf(fmaxf(__fmul_rn(w, h), 1e-6f));
    float l2 = (float)log2((double)__fadd_rn(__fdiv_rn(s, 224.0f), 1e-8f));
    float lv = floorf(__fadd_rn(4.0f, l2));
    lv = fminf(fmaxf(lv, 2.0f), 5.0f);
    int lvl = (int)lv - 2;

    int H, W; float scale;
    if (lvl == 0)      { H = 200; W = 304; scale = 0.25f; }
    else if (lvl == 1) { H = 100; W = 152; scale = 0.125f; }
    else if (lvl == 2) { H = 50;  W = 76;  scale = 0.0625f; }
    else               { H = 25;  W = 38;  scale = 0.03125f; }

    float xs1 = __fmul_rn(x1, scale), ys1 = __fmul_rn(y1, scale);
    float xs2 = __fmul_rn(x2, scale), ys2 = __fmul_rn(y2, scale);
    float bw = __fdiv_rn(fmaxf(__fsub_rn(xs2, xs1), 1.0f), 7.0f);
    float bh = __fdiv_rn(fmaxf(__fsub_rn(ys2, ys1), 1.0f), 7.0f);

    int* pb = prep + b * 20;
    pb[0] = lvl;
    pb[1] = n * CCH * H * W;
    pb[2] = H * W;
#pragma unroll
    for (int i = 0; i < 7; i++) {
        float cs = (float)i + 0.5f;
        float gx = __fadd_rn(xs1, __fmul_rn(cs, bw));
        float gy = __fadd_rn(ys1, __fmul_rn(cs, bh));
        int vx = (int)gx;
        int vy = (int)gy;
        vx = vx < 0 ? 0 : (vx > W - 1 ? W - 1 : vx);
        vy = vy < 0 ? 0 : (vy > H - 1 ? H - 1 : vy);
        pb[4 + i] = vx;
        pb[12 + i] = vy * W;
    }
}

// ================= Panel-parallel FC1 (exact round-13 version: 720 us proven) =================
#define FMASTEP(KB, WV)                                               \
    {                                                                 \
        const float4* xv = (const float4*)&xs[(KB)][0];               \
        float4 a0 = xv[0], a1 = xv[1], a2 = xv[2], a3 = xv[3];        \
        float xr[16] = {a0.x, a0.y, a0.z, a0.w, a1.x, a1.y, a1.z, a1.w, \
                        a2.x, a2.y, a2.z, a2.w, a3.x, a3.y, a3.z, a3.w}; \
        _Pragma("unroll")                                             \
        for (int r = 0; r < RB; r++) {                                \
            acc[r][0] = fmaf(xr[r], WV.x, acc[r][0]);                 \
            acc[r][1] = fmaf(xr[r], WV.y, acc[r][1]);                 \
            acc[r][2] = fmaf(xr[r], WV.z, acc[r][2]);                 \
            acc[r][3] = fmaf(xr[r], WV.w, acc[r][3]);                 \
        }                                                             \
    }

__global__ __launch_bounds__(256, 4) void fc1_panel(
    const float* __restrict__ p2, const float* __restrict__ p3,
    const float* __restrict__ p4, const float* __restrict__ p5,
    const int* __restrict__ prep, const float* __restrict__ W1,
    float* __restrict__ part, int g0, int gs) {
    __shared__ float xs[CHUNK][RB];
    __shared__ int s_ix[RB][7], s_iyW[RB][7], s_HW[RB];
    __shared__ const float* s_fp[RB];

    int tid = threadIdx.x;
    int gy = blockIdx.x;
    int p = blockIdx.y;
    int row0 = (g0 + gy) * RB;
    int k0 = p * KC;
    int kt = (p == NPANEL - 1) ? 256 : KC;

    if (tid < RB) {
        const int* pb = prep + (row0 + tid) * 20;
        int lvl = pb[0];
        s_fp[tid] = (lvl == 0 ? p2 : lvl == 1 ? p3 : lvl == 2 ? p4 : p5) + pb[1];
        s_HW[tid] = pb[2];
#pragma unroll
        for (int j = 0; j < 7; j++) { s_ix[tid][j] = pb[4 + j]; s_iyW[tid][j] = pb[12 + j]; }
    }
    __syncthreads();

    float acc[RB][4];
#pragma unroll
    for (int r = 0; r < RB; r++)
#pragma unroll
        for (int j = 0; j < 4; j++) acc[r][j] = 0.0f;

    const float* wp = W1 + (size_t)k0 * FCD + tid * 4;

    for (int ck = 0; ck < kt; ck += CHUNK) {
        for (int e = tid; e < CHUNK * RB; e += 256) {
            int kk = e >> 4;
            int r = e & 15;
            int k = k0 + ck + kk;
            int c = k / 49;
            int pp = k - c * 49;
            int gyy = pp / 7;
            int gxx = pp - gyy * 7;
            xs[kk][r] = s_fp[r][c * s_HW[r] + s_iyW[r][gyy] + s_ix[r][gxx]];
        }
        __syncthreads();

        const float* wc = wp + (size_t)ck * FCD;
        float4 wA = *(const float4*)wc;
        for (int kk = 0; kk < CHUNK; kk += 2) {
            float4 wB = *(const float4*)(wc + (size_t)(kk + 1) * FCD);
            FMASTEP(kk, wA)                   // k ascending: chain order preserved
            if (kk + 2 < CHUNK) wA = *(const float4*)(wc + (size_t)(kk + 2) * FCD);
            FMASTEP(kk + 1, wB)
        }
        __syncthreads();
    }

    size_t pstride = (size_t)gs * RB * FCD;
    float* po = part + (size_t)p * pstride + ((size_t)gy * RB) * FCD + tid * 4;
#pragma unroll
    for (int r = 0; r < RB; r++) {
        float4 v = make_float4(acc[r][0], acc[r][1], acc[r][2], acc[r][3]);
        *(float4*)(po + (size_t)r * FCD) = v;
    }
}

// ================= Panel-parallel FC2 =================
__global__ __launch_bounds__(256, 4) void fc2_panel(
    const float* __restrict__ X1, const float* __restrict__ W2,
    float* __restrict__ part) {
    __shared__ float xs2[CHUNK][RB2];
    int tid = threadIdx.x;
    int gy = blockIdx.x;
    int p = blockIdx.y;
    int row0 = gy * RB2;
    int k0 = p * KC;
    int kt = (p == NP2 - 1) ? 256 : KC;

    float acc[RB2][4];
#pragma unroll
    for (int r = 0; r < RB2; r++)
#pragma unroll
        for (int j = 0; j < 4; j++) acc[r][j] = 0.0f;

    const float* wp = W2 + (size_t)k0 * FCD + tid * 4;

    for (int ck = 0; ck < kt; ck += CHUNK) {
        for (int e = tid; e < CHUNK * RB2; e += 256) {
            int kk = e >> 3;
            int r = e & 7;
            xs2[kk][r] = X1[(size_t)(row0 + r) * FCD + k0 + ck + kk];
        }
        __syncthreads();

        const float* wc = wp + (size_t)ck * FCD;
        float4 wA = *(const float4*)wc;
        for (int kk = 0; kk < CHUNK; kk += 2) {
            float4 wB = *(const float4*)(wc + (size_t)(kk + 1) * FCD);
            {
                const float4* xv = (const float4*)&xs2[kk][0];
                float4 a0 = xv[0], a1 = xv[1];
                float xr[8] = {a0.x, a0.y, a0.z, a0.w, a1.x, a1.y, a1.z, a1.w};
#pragma unroll
                for (int r = 0; r < RB2; r++) {
                    acc[r][0] = fmaf(xr[r], wA.x, acc[r][0]);
                    acc[r][1] = fmaf(xr[r], wA.y, acc[r][1]);
                    acc[r][2] = fmaf(xr[r], wA.z, acc[r][2]);
                    acc[r][3] = fmaf(xr[r], wA.w, acc[r][3]);
                }
            }
            if (kk + 2 < CHUNK) wA = *(const float4*)(wc + (size_t)(kk + 2) * FCD);
            {
                const float4* xv = (const float4*)&xs2[kk + 1][0];
                float4 a0 = xv[0], a1 = xv[1];
                float xr[8] = {a0.x, a0.y, a0.z, a0.w, a1.x, a1.y, a1.z, a1.w};
#pragma unroll
                for (int r = 0; r < RB2; r++) {
                    acc[r][0] = fmaf(xr[r], wB.x, acc[r][0]);
                    acc[r][1] = fmaf(xr[r], wB.y, acc[r][1]);
                    acc[r][2] = fmaf(xr[r], wB.z, acc[r][2]);
                    acc[r][3] = fmaf(xr[r], wB.w, acc[r][3]);
                }
            }
        }
        __syncthreads();
    }

    size_t pstride = (size_t)NIMG * NBOX * FCD;
    float* po = part + (size_t)p * pstride + ((size_t)row0) * FCD + tid * 4;
#pragma unroll
    for (int r = 0; r < RB2; r++) {
        float4 v = make_float4(acc[r][0], acc[r][1], acc[r][2], acc[r][3]);
        *(float4*)(po + (size_t)r * FCD) = v;
    }
}

// Ordered left-fold over panel chains + bias + ReLU. Exact OpenBLAS panel fold.
__global__ void fold_bias_relu(const float* __restrict__ part, const float* __restrict__ bias,
                               float* __restrict__ Xout, int row_base, int rows_s, int npanel) {
    int idx = blockIdx.x * 256 + threadIdx.x;
    if (idx >= rows_s * FCD) return;
    size_t stride = (size_t)rows_s * FCD;
    float tot = part[idx];
    for (int p = 1; p < npanel; p++)
        tot = __fadd_rn(tot, part[(size_t)p * stride + idx]);
    int c = idx & (FCD - 1);
    float v = __fadd_rn(tot, bias[c]);
    Xout[(size_t)row_base * FCD + idx] = fmaxf(v, 0.0f);
}

// ================= fallback machinery (round-10, proven bit-exact) =================
#define FMA8(BUF, KB)                                                                   \
    _Pragma("unroll")                                                                   \
    for (int u = 0; u < 8; u++) {                                                       \
        const float4* xv = (const float4*)&xs[(KB) + u][0];                             \
        float4 a0 = xv[0], a1 = xv[1];                                                  \
        float wx = BUF[u].x, wy = BUF[u].y;                                             \
        acc[0][0] = fmaf(a0.x, wx, acc[0][0]); acc[0][1] = fmaf(a0.x, wy, acc[0][1]);   \
        acc[1][0] = fmaf(a0.y, wx, acc[1][0]); acc[1][1] = fmaf(a0.y, wy, acc[1][1]);   \
        acc[2][0] = fmaf(a0.z, wx, acc[2][0]); acc[2][1] = fmaf(a0.z, wy, acc[2][1]);   \
        acc[3][0] = fmaf(a0.w, wx, acc[3][0]); acc[3][1] = fmaf(a0.w, wy, acc[3][1]);   \
        acc[4][0] = fmaf(a1.x, wx, acc[4][0]); acc[4][1] = fmaf(a1.x, wy, acc[4][1]);   \
        acc[5][0] = fmaf(a1.y, wx, acc[5][0]); acc[5][1] = fmaf(a1.y, wy, acc[5][1]);   \
        acc[6][0] = fmaf(a1.z, wx, acc[6][0]); acc[6][1] = fmaf(a1.z, wy, acc[6][1]);   \
        acc[7][0] = fmaf(a1.w, wx, acc[7][0]); acc[7][1] = fmaf(a1.w, wy, acc[7][1]);   \
    }

template <int KT>
__device__ __forceinline__ void fc_panel2(const float* __restrict__ wp,
                                          const float (*xs)[R1],
                                          float acc[R1][2]) {
    float2 wa[8], wb[8];
#pragma unroll
    for (int u = 0; u < 8; u++) wa[u] = *(const float2*)(wp + (size_t)u * FCD);
    for (int kk = 0; kk < KT; kk += 16) {
#pragma unroll
        for (int u = 0; u < 8; u++)
            wb[u] = *(const float2*)(wp + (size_t)(kk + 8 + u) * FCD);
        FMA8(wa, kk)
        if (kk + 16 < KT) {
#pragma unroll
            for (int u = 0; u < 8; u++)
                wa[u] = *(const float2*)(wp + (size_t)(kk + 16 + u) * FCD);
        }
        FMA8(wb, kk + 8)
    }
}

__global__ __launch_bounds__(256) void fc1_fallback(
    const float* __restrict__ p2, const float* __restrict__ p3,
    const float* __restrict__ p4, const float* __restrict__ p5,
    const int* __restrict__ prep, const float* __restrict__ W1,
    const float* __restrict__ b1, float* __restrict__ X1) {
    __shared__ float xs[KC][R1];
    __shared__ int s_ix[R1][7], s_iyW[R1][7], s_HW[R1];
    __shared__ const float* s_fp[R1];

    int tid = threadIdx.x;
    int c0 = blockIdx.x * 512 + tid * 2;
    int row0 = blockIdx.y * R1;

    if (tid < R1) {
        const int* pb = prep + (row0 + tid) * 20;
        int lvl = pb[0];
        s_fp[tid] = (lvl == 0 ? p2 : lvl == 1 ? p3 : lvl == 2 ? p4 : p5) + pb[1];
        s_HW[tid] = pb[2];
#pragma unroll
        for (int j = 0; j < 7; j++) { s_ix[tid][j] = pb[4 + j]; s_iyW[tid][j] = pb[12 + j]; }
    }

    float tot[R1][2];
#pragma unroll
    for (int r = 0; r < R1; r++) { tot[r][0] = 0.0f; tot[r][1] = 0.0f; }

    for (int k0 = 0; k0 < FCIN; k0 += KC) {
        int kt = FCIN - k0; if (kt > KC) kt = KC;
        __syncthreads();
        for (int e = tid; e < kt * R1; e += 256) {
            int kk = e >> 3;
            int r = e & 7;
            int k = k0 + kk;
            int c = k / 49;
            int p = k - c * 49;
            int gy = p / 7;
            int gx = p - gy * 7;
            xs[kk][r] = s_fp[r][c * s_HW[r] + s_iyW[r][gy] + s_ix[r][gx]];
        }
        __syncthreads();

        float acc[R1][2];
#pragma unroll
        for (int r = 0; r < R1; r++) { acc[r][0] = 0.0f; acc[r][1] = 0.0f; }

        const float* wp = W1 + (size_t)k0 * FCD + c0;
        if (kt == KC) fc_panel2<KC>(wp, xs, acc);
        else          fc_panel2<256>(wp, xs, acc);

#pragma unroll
        for (int r = 0; r < R1; r++) {
            tot[r][0] = __fadd_rn(tot[r][0], acc[r][0]);
            tot[r][1] = __fadd_rn(tot[r][1], acc[r][1]);
        }
    }
    float bv0 = b1[c0], bv1 = b1[c0 + 1];
#pragma unroll
    for (int r = 0; r < R1; r++) {
        float v0 = __fadd_rn(tot[r][0], bv0);
        float v1 = __fadd_rn(tot[r][1], bv1);
        X1[(size_t)(row0 + r) * FCD + c0]     = fmaxf(v0, 0.0f);
        X1[(size_t)(row0 + r) * FCD + c0 + 1] = fmaxf(v1, 0.0f);
    }
}

__global__ __launch_bounds__(256) void fc2_seq(
    const float* __restrict__ X1, const float* __restrict__ W2,
    const float* __restrict__ b2, float* __restrict__ X2) {
    __shared__ float xs[KC][R1];
    int tid = threadIdx.x;
    int c0 = blockIdx.x * 512 + tid * 2;
    int row0 = blockIdx.y * R1;

    float tot[R1][2];
#pragma unroll
    for (int r = 0; r < R1; r++) { tot[r][0] = 0.0f; tot[r][1] = 0.0f; }

    for (int k0 = 0; k0 < FCD; k0 += KC) {
        int kt = FCD - k0; if (kt > KC) kt = KC;
        __syncthreads();
        for (int e = tid; e < kt * R1; e += 256) {
            int kk = e >> 3;
            int r = e & 7;
            xs[kk][r] = X1[(size_t)(row0 + r) * FCD + k0 + kk];
        }
        __syncthreads();

        float acc[R1][2];
#pragma unroll
        for (int r = 0; r < R1; r++) { acc[r][0] = 0.0f; acc[r][1] = 0.0f; }

        const float* wp = W2 + (size_t)k0 * FCD + c0;
        if (kt == KC) fc_panel2<KC>(wp, xs, acc);
        else          fc_panel2<256>(wp, xs, acc);

#pragma unroll
        for (int r = 0; r < R1; r++) {
            tot[r][0] = __fadd_rn(tot[r][0], acc[r][0]);
            tot[r][1] = __fadd_rn(tot[r][1], acc[r][1]);
        }
    }
    float bv0 = b2[c0], bv1 = b2[c0 + 1];
#pragma unroll
    for (int r = 0; r < R1; r++) {
        float v0 = __fadd_rn(tot[r][0], bv0);
        float v1 = __fadd_rn(tot[r][1], bv1);
        X2[(size_t)(row0 + r) * FCD + c0]     = fmaxf(v0, 0.0f);
        X2[(size_t)(row0 + r) * FCD + c0 + 1] = fmaxf(v1, 0.0f);
    }
}

// ---------------- Heads, parallel: 8 boxes/block, 18 chains per box (q x panel) ----------------
// Chain (q,p): ascending-k fmaf over panel p -- identical order to heads_seq.
// Fold: ((c0+c1)+c2)+bias == heads_seq's ((0+c0)+c1)+c2)+bias (0+c0 exact).
__global__ __launch_bounds__(256) void heads_par(
    const float* __restrict__ X2,
    const float* __restrict__ Wc, const float* __restrict__ bc,
    const float* __restrict__ Wb, const float* __restrict__ bb_,
    const float* __restrict__ props, const int* __restrict__ img_sz,
    float* __restrict__ SC, float* __restrict__ BX) {
    int tid = threadIdx.x;
    int b0 = blockIdx.x * HB;
    __shared__ float xsh[HB][FCD];    // 32 KB
    __shared__ float wsh[6][FCD];     // 24 KB
    __shared__ float red[HB][6][3];
    __shared__ float lg[HB][6];

    for (int e = tid; e < HB * FCD; e += 256) {
        int r = e >> 10, k = e & (FCD - 1);
        xsh[r][k] = X2[(size_t)(b0 + r) * FCD + k];
    }
    for (int e = tid; e < 6 * FCD; e += 256) {
        int q = e / FCD, k = e - q * FCD;
        wsh[q][k] = (q < 2) ? Wc[k * 2 + q] : Wb[k * 4 + (q - 2)];
    }
    __syncthreads();

    int c = tid & 31, r = tid >> 5;   // r: box in block, c: chain slot
    if (c < 18) {
        int q = c / 3, p = c - q * 3;
        int k0 = p * KC;
        int kt = (p == 2) ? 256 : KC;
        float acc = 0.0f;
        for (int k = k0; k < k0 + kt; k++)
            acc = fmaf(xsh[r][k], wsh[q][k], acc);
        red[r][q][p] = acc;
    }
    __syncthreads();

    if (c < 6) {
        int q = c;
        float t = __fadd_rn(__fadd_rn(red[r][q][0], red[r][q][1]), red[r][q][2]);
        float bias = (q < 2) ? bc[q] : bb_[q - 2];
        lg[r][q] = __fadd_rn(t, bias);
    }
    __syncthreads();

    if (c == 0) {
        int b = b0 + r;
        float c0 = lg[r][0], c1 = lg[r][1];
        float mx = fmaxf(c0, c1);
        float e0 = (float)exp((double)__fsub_rn(c0, mx));
        float e1 = (float)exp((double)__fsub_rn(c1, mx));
        SC[b] = __fdiv_rn(e1, __fadd_rn(e0, e1));

        int n = b / NBOX;
        const float* pr = props + (size_t)b * 4;
        float x1 = pr[0], y1 = pr[1], x2 = pr[2], y2 = pr[3];
        float w = __fsub_rn(x2, x1), h = __fsub_rn(y2, y1);
        float cx = __fadd_rn(x1, __fmul_rn(0.5f, w));
        float cy = __fadd_rn(y1, __fmul_rn(0.5f, h));
        float dx = lg[r][2], dy = lg[r][3];
        float dw = fminf(lg[r][4], SCALE_CLAMP_F);
        float dh = fminf(lg[r][5], SCALE_CLAMP_F);
        float pcx = __fadd_rn(__fmul_rn(dx, w), cx);
        float pcy = __fadd_rn(__fmul_rn(dy, h), cy);
        float pw = __fmul_rn((float)exp((double)dw), w);
        float ph = __fmul_rn((float)exp((double)dh), h);
        float bx1 = __fsub_rn(pcx, __fmul_rn(0.5f, pw));
        float by1 = __fsub_rn(pcy, __fmul_rn(0.5f, ph));
        float bx2 = __fadd_rn(pcx, __fmul_rn(0.5f, pw));
        float by2 = __fadd_rn(pcy, __fmul_rn(0.5f, ph));
        float Hf = (float)img_sz[n * 2 + 0], Wf = (float)img_sz[n * 2 + 1];
        bx1 = fminf(fmaxf(bx1, 0.0f), Wf);
        by1 = fminf(fmaxf(by1, 0.0f), Hf);
        bx2 = fminf(fmaxf(bx2, 0.0f), Wf);
        by2 = fminf(fmaxf(by2, 0.0f), Hf);
        BX[(size_t)b * 4 + 0] = bx1;
        BX[(size_t)b * 4 + 1] = by1;
        BX[(size_t)b * 4 + 2] = bx2;
        BX[(size_t)b * 4 + 3] = by2;
    }
}

// ---------------- Sort + NMS + topk (strict f32, numpy op order) ----------------
__global__ __launch_bounds__(1024) void nms_kernel(const float* __restrict__ SC,
                                                   const float* __restrict__ BX,
                                                   float* __restrict__ out) {
    int n = blockIdx.x;
    __shared__ float sraw[NBOX];
    __shared__ float ssort[NBOX];
    __shared__ float bsort[NBOX][4];
    __shared__ int ord[NBOX];
    __shared__ unsigned char keep[NBOX];
    int tid = threadIdx.x;

    for (int j = tid; j < NBOX; j += 1024) sraw[j] = SC[n * NBOX + j];
    __syncthreads();

    if (tid < NBOX) {
        float sj = sraw[tid];
        int r = 0;
        for (int k = 0; k < NBOX; k++) {
            float sk = sraw[k];
            r += (sk > sj) || (sk == sj && k < tid);
        }
        ord[r] = tid;
        ssort[r] = sj;
#pragma unroll
        for (int k = 0; k < 4; k++) bsort[r][k] = BX[((size_t)n * NBOX + tid) * 4 + k];
        keep[r] = (sj > 0.05f) ? 1 : 0;
    }
    __syncthreads();

    for (int i = 0; i < NBOX - 1; i++) {
        if (keep[i] && tid > i && tid < NBOX && keep[tid]) {
            float ax1 = bsort[i][0], ay1 = bsort[i][1], ax2 = bsort[i][2], ay2 = bsort[i][3];
            float bx1 = bsort[tid][0], by1 = bsort[tid][1], bx2 = bsort[tid][2], by2 = bsort[tid][3];
            float areaA = __fmul_rn(__fsub_rn(ax2, ax1), __fsub_rn(ay2, ay1));
            float areaB = __fmul_rn(__fsub_rn(bx2, bx1), __fsub_rn(by2, by1));
            float ix1 = fmaxf(ax1, bx1), iy1 = fmaxf(ay1, by1);
            float ix2 = fminf(ax2, bx2), iy2 = fminf(ay2, by2);
            float iw = fmaxf(__fsub_rn(ix2, ix1), 0.0f);
            float ih = fmaxf(__fsub_rn(iy2, iy1), 0.0f);
            float inter = __fmul_rn(iw, ih);
            float denom = fmaxf(__fsub_rn(__fadd_rn(areaA, areaB), inter), 1e-9f);
            if (__fdiv_rn(inter, denom) > 0.5f) keep[tid] = 0;
        }
        __syncthreads();
    }

    if (tid == 0) {
        int c = 0;
        for (int r = 0; r < NBOX; r++) {
            int k = keep[r];
            c += k;
            keep[r] = (k && (c <= TOPK)) ? 1 : 0;
        }
    }
    __syncthreads();

    float* boxes_o = out;
    float* scores_o = out + (size_t)NIMG * NBOX * 4;
    float* keep_o = scores_o + (size_t)NIMG * NBOX;
    float* ord_o = keep_o + (size_t)NIMG * NBOX;
    for (int r = tid; r < NBOX; r += 1024) {
#pragma unroll
        for (int k = 0; k < 4; k++)
            boxes_o[((size_t)n * NBOX + r) * 4 + k] = bsort[r][k];
        scores_o[n * NBOX + r] = ssort[r];
        keep_o[n * NBOX + r] = (float)keep[r];
        ord_o[n * NBOX + r] = (float)ord[r];
    }
}

extern "C" void kernel_launch(void* const* d_in, const int* in_sizes, int n_in,
                              void* d_out, int out_size, void* d_ws, size_t ws_size,
                              hipStream_t stream) {
    const float* p2 = (const float*)d_in[0];
    const float* p3 = (const float*)d_in[1];
    const float* p4 = (const float*)d_in[2];
    const float* p5 = (const float*)d_in[3];
    const float* props = (const float*)d_in[4];
    const int* img = (const int*)d_in[5];
    const float* W1 = (const float*)d_in[6];
    const float* b1 = (const float*)d_in[7];
    const float* W2 = (const float*)d_in[8];
    const float* b2 = (const float*)d_in[9];
    const float* Wc = (const float*)d_in[10];
    const float* bc = (const float*)d_in[11];
    const float* Wb = (const float*)d_in[12];
    const float* bb = (const float*)d_in[13];

    float* X1 = (float*)d_ws;
    float* X2 = X1 + (size_t)2000 * FCD;
    float* SCf = X2 + (size_t)2000 * FCD;
    float* BXf = SCf + 2000;
    int* prep = (int*)(BXf + 8000);
    float* part = (float*)(prep + 2000 * 20);
    size_t used = (size_t)((char*)part - (char*)d_ws);
    size_t avail = ws_size > used ? ws_size - used : 0;

    prep_kernel<<<(NIMG * NBOX + 255) / 256, 256, 0, stream>>>(props, prep);

    // fc1: single sweep preferred (round-13/15 proven optimum: 720 us)
    int gmax = 0;
    const int cand[4] = {125, 63, 32, 16};
    for (int i = 0; i < 4; i++) {
        size_t need = (size_t)NPANEL * cand[i] * RB * FCD * sizeof(float);
        if (need <= avail) { gmax = cand[i]; break; }
    }

    if (gmax > 0) {
        for (int g0 = 0; g0 < NGROUP; g0 += gmax) {
            int gs = NGROUP - g0; if (gs > gmax) gs = gmax;
            dim3 gA(gs, NPANEL);
            fc1_panel<<<gA, 256, 0, stream>>>(p2, p3, p4, p5, prep, W1, part, g0, gs);
            int nelem = gs * RB * FCD;
            fold_bias_relu<<<(nelem + 255) / 256, 256, 0, stream>>>(part, b1, X1,
                                                                    g0 * RB, gs * RB, NPANEL);
        }
    } else {
        dim3 gfc(2, (NIMG * NBOX) / R1);
        fc1_fallback<<<gfc, 256, 0, stream>>>(p2, p3, p4, p5, prep, W1, b1, X1);
    }

    // fc2: panel-parallel if partial buffer fits (24.6 MB), else proven fc2_seq
    size_t need2 = (size_t)NP2 * NIMG * NBOX * FCD * sizeof(float);
    if (need2 <= avail) {
        dim3 g2(NIMG * NBOX / RB2, NP2);           // (250, 3)
        fc2_panel<<<g2, 256, 0, stream>>>(X1, W2, part);
        int nelem2 = NIMG * NBOX * FCD;
        fold_bias_relu<<<(nelem2 + 255) / 256, 256, 0, stream>>>(part, b2, X2,
                                                                 0, NIMG * NBOX, NP2);
    } else {
        dim3 gfc2(2, (NIMG * NBOX) / R1);
        fc2_seq<<<gfc2, 256, 0, stream>>>(X1, W2, b2, X2);
    }

    heads_par<<<NIMG * NBOX / HB, 256, 0, stream>>>(X2, Wc, bc, Wb, bb, props, img, SCf, BXf);

    nms_kernel<<<NIMG, 1024, 0, stream>>>(SCf, BXf, (float*)d_out);
}

// Round 18
// 1114.887 us; speedup vs baseline: 1.1200x; 1.0425x over previous
//
#include <hip/hip_runtime.h>
#include <math.h>

#define NBOX 1000
#define NIMG 2
#define CCH 256
#define FCIN 12544   // 256*7*7
#define FCD 1024
#define TOPK 100
#define SCALE_CLAMP_F ((float)4.135166556742356)  // f32(np.log(1000/16))
#define KC 384       // OpenBLAS SGEMM_DEFAULT_Q -- FROZEN numerics invariant
#define NPANEL 33    // 12544 = 32*384 + 256
#define RB 16        // rows per fc1 panel-block
#define NGROUP 125   // 2000/16
#define CHUNK 128    // LDS staging chunk (divides 384 and 256)
#define RB2 8        // rows per fc2 panel-block
#define NP2 3        // fc2 panels: 384,384,256
#define R1 8         // rows per block, fallback path
#define HB 8         // boxes per heads block
#define NW 16        // u64 words covering 1000 rank bits

// ---------------- Prep: per-box level + gather indices (strict f32, numpy op order) ----------------
__global__ void prep_kernel(const float* __restrict__ props, int* __restrict__ prep) {
    int b = blockIdx.x * blockDim.x + threadIdx.x;
    if (b >= NIMG * NBOX) return;
    int n = b / NBOX;
    const float* pr = props + (size_t)b * 4;
    float x1 = pr[0], y1 = pr[1], x2 = pr[2], y2 = pr[3];

    float w = __fsub_rn(x2, x1), h = __fsub_rn(y2, y1);
    float s = sqrtf(fmaxf(__fmul_rn(w, h), 1e-6f));
    float l2 = (float)log2((double)__fadd_rn(__fdiv_rn(s, 224.0f), 1e-8f));
    float lv = floorf(__fadd_rn(4.0f, l2));
    lv = fminf(fmaxf(lv, 2.0f), 5.0f);
    int lvl = (int)lv - 2;

    int H, W; float scale;
    if (lvl == 0)      { H = 200; W = 304; scale = 0.25f; }
    else if (lvl == 1) { H = 100; W = 152; scale = 0.125f; }
    else if (lvl == 2) { H = 50;  W = 76;  scale = 0.0625f; }
    else               { H = 25;  W = 38;  scale = 0.03125f; }

    float xs1 = __fmul_rn(x1, scale), ys1 = __fmul_rn(y1, scale);
    float xs2 = __fmul_rn(x2, scale), ys2 = __fmul_rn(y2, scale);
    float bw = __fdiv_rn(fmaxf(__fsub_rn(xs2, xs1), 1.0f), 7.0f);
    float bh = __fdiv_rn(fmaxf(__fsub_rn(ys2, ys1), 1.0f), 7.0f);

    int* pb = prep + b * 20;
    pb[0] = lvl;
    pb[1] = n * CCH * H * W;
    pb[2] = H * W;
#pragma unroll
    for (int i = 0; i < 7; i++) {
        float cs = (float)i + 0.5f;
        float gx = __fadd_rn(xs1, __fmul_rn(cs, bw));
        float gy = __fadd_rn(ys1, __fmul_rn(cs, bh));
        int vx = (int)gx;
        int vy = (int)gy;
        vx = vx < 0 ? 0 : (vx > W - 1 ? W - 1 : vx);
        vy = vy < 0 ? 0 : (vy > H - 1 ? H - 1 : vy);
        pb[4 + i] = vx;
        pb[12 + i] = vy * W;
    }
}

// ================= Panel-parallel FC1 (round-13 version: 720 us, 3x-confirmed) =================
#define FMASTEP(KB, WV)                                               \
    {                                                                 \
        const float4* xv = (const float4*)&xs[(KB)][0];               \
        float4 a0 = xv[0], a1 = xv[1], a2 = xv[2], a3 = xv[3];        \
        float xr[16] = {a0.x, a0.y, a0.z, a0.w, a1.x, a1.y, a1.z, a1.w, \
                        a2.x, a2.y, a2.z, a2.w, a3.x, a3.y, a3.z, a3.w}; \
        _Pragma("unroll")                                             \
        for (int r = 0; r < RB; r++) {                                \
            acc[r][0] = fmaf(xr[r], WV.x, acc[r][0]);                 \
            acc[r][1] = fmaf(xr[r], WV.y, acc[r][1]);                 \
            acc[r][2] = fmaf(xr[r], WV.z, acc[r][2]);                 \
            acc[r][3] = fmaf(xr[r], WV.w, acc[r][3]);                 \
        }                                                             \
    }

__global__ __launch_bounds__(256, 4) void fc1_panel(
    const float* __restrict__ p2, const float* __restrict__ p3,
    const float* __restrict__ p4, const float* __restrict__ p5,
    const int* __restrict__ prep, const float* __restrict__ W1,
    float* __restrict__ part, int g0, int gs) {
    __shared__ float xs[CHUNK][RB];
    __shared__ int s_ix[RB][7], s_iyW[RB][7], s_HW[RB];
    __shared__ const float* s_fp[RB];

    int tid = threadIdx.x;
    int gy = blockIdx.x;
    int p = blockIdx.y;
    int row0 = (g0 + gy) * RB;
    int k0 = p * KC;
    int kt = (p == NPANEL - 1) ? 256 : KC;

    if (tid < RB) {
        const int* pb = prep + (row0 + tid) * 20;
        int lvl = pb[0];
        s_fp[tid] = (lvl == 0 ? p2 : lvl == 1 ? p3 : lvl == 2 ? p4 : p5) + pb[1];
        s_HW[tid] = pb[2];
#pragma unroll
        for (int j = 0; j < 7; j++) { s_ix[tid][j] = pb[4 + j]; s_iyW[tid][j] = pb[12 + j]; }
    }
    __syncthreads();

    float acc[RB][4];
#pragma unroll
    for (int r = 0; r < RB; r++)
#pragma unroll
        for (int j = 0; j < 4; j++) acc[r][j] = 0.0f;

    const float* wp = W1 + (size_t)k0 * FCD + tid * 4;

    for (int ck = 0; ck < kt; ck += CHUNK) {
        for (int e = tid; e < CHUNK * RB; e += 256) {
            int kk = e >> 4;
            int r = e & 15;
            int k = k0 + ck + kk;
            int c = k / 49;
            int pp = k - c * 49;
            int gyy = pp / 7;
            int gxx = pp - gyy * 7;
            xs[kk][r] = s_fp[r][c * s_HW[r] + s_iyW[r][gyy] + s_ix[r][gxx]];
        }
        __syncthreads();

        const float* wc = wp + (size_t)ck * FCD;
        float4 wA = *(const float4*)wc;
        for (int kk = 0; kk < CHUNK; kk += 2) {
            float4 wB = *(const float4*)(wc + (size_t)(kk + 1) * FCD);
            FMASTEP(kk, wA)                   // k ascending: chain order preserved
            if (kk + 2 < CHUNK) wA = *(const float4*)(wc + (size_t)(kk + 2) * FCD);
            FMASTEP(kk + 1, wB)
        }
        __syncthreads();
    }

    size_t pstride = (size_t)gs * RB * FCD;
    float* po = part + (size_t)p * pstride + ((size_t)gy * RB) * FCD + tid * 4;
#pragma unroll
    for (int r = 0; r < RB; r++) {
        float4 v = make_float4(acc[r][0], acc[r][1], acc[r][2], acc[r][3]);
        *(float4*)(po + (size_t)r * FCD) = v;
    }
}

// ================= Panel-parallel FC2 =================
__global__ __launch_bounds__(256, 4) void fc2_panel(
    const float* __restrict__ X1, const float* __restrict__ W2,
    float* __restrict__ part) {
    __shared__ float xs2[CHUNK][RB2];
    int tid = threadIdx.x;
    int gy = blockIdx.x;
    int p = blockIdx.y;
    int row0 = gy * RB2;
    int k0 = p * KC;
    int kt = (p == NP2 - 1) ? 256 : KC;

    float acc[RB2][4];
#pragma unroll
    for (int r = 0; r < RB2; r++)
#pragma unroll
        for (int j = 0; j < 4; j++) acc[r][j] = 0.0f;

    const float* wp = W2 + (size_t)k0 * FCD + tid * 4;

    for (int ck = 0; ck < kt; ck += CHUNK) {
        for (int e = tid; e < CHUNK * RB2; e += 256) {
            int kk = e >> 3;
            int r = e & 7;
            xs2[kk][r] = X1[(size_t)(row0 + r) * FCD + k0 + ck + kk];
        }
        __syncthreads();

        const float* wc = wp + (size_t)ck * FCD;
        float4 wA = *(const float4*)wc;
        for (int kk = 0; kk < CHUNK; kk += 2) {
            float4 wB = *(const float4*)(wc + (size_t)(kk + 1) * FCD);
            {
                const float4* xv = (const float4*)&xs2[kk][0];
                float4 a0 = xv[0], a1 = xv[1];
                float xr[8] = {a0.x, a0.y, a0.z, a0.w, a1.x, a1.y, a1.z, a1.w};
#pragma unroll
                for (int r = 0; r < RB2; r++) {
                    acc[r][0] = fmaf(xr[r], wA.x, acc[r][0]);
                    acc[r][1] = fmaf(xr[r], wA.y, acc[r][1]);
                    acc[r][2] = fmaf(xr[r], wA.z, acc[r][2]);
                    acc[r][3] = fmaf(xr[r], wA.w, acc[r][3]);
                }
            }
            if (kk + 2 < CHUNK) wA = *(const float4*)(wc + (size_t)(kk + 2) * FCD);
            {
                const float4* xv = (const float4*)&xs2[kk + 1][0];
                float4 a0 = xv[0], a1 = xv[1];
                float xr[8] = {a0.x, a0.y, a0.z, a0.w, a1.x, a1.y, a1.z, a1.w};
#pragma unroll
                for (int r = 0; r < RB2; r++) {
                    acc[r][0] = fmaf(xr[r], wB.x, acc[r][0]);
                    acc[r][1] = fmaf(xr[r], wB.y, acc[r][1]);
                    acc[r][2] = fmaf(xr[r], wB.z, acc[r][2]);
                    acc[r][3] = fmaf(xr[r], wB.w, acc[r][3]);
                }
            }
        }
        __syncthreads();
    }

    size_t pstride = (size_t)NIMG * NBOX * FCD;
    float* po = part + (size_t)p * pstride + ((size_t)row0) * FCD + tid * 4;
#pragma unroll
    for (int r = 0; r < RB2; r++) {
        float4 v = make_float4(acc[r][0], acc[r][1], acc[r][2], acc[r][3]);
        *(float4*)(po + (size_t)r * FCD) = v;
    }
}

// Ordered left-fold over panel chains + bias + ReLU. Exact OpenBLAS panel fold.
__global__ void fold_bias_relu(const float* __restrict__ part, const float* __restrict__ bias,
                               float* __restrict__ Xout, int row_base, int rows_s, int npanel) {
    int idx = blockIdx.x * 256 + threadIdx.x;
    if (idx >= rows_s * FCD) return;
    size_t stride = (size_t)rows_s * FCD;
    float tot = part[idx];
    for (int p = 1; p < npanel; p++)
        tot = __fadd_rn(tot, part[(size_t)p * stride + idx]);
    int c = idx & (FCD - 1);
    float v = __fadd_rn(tot, bias[c]);
    Xout[(size_t)row_base * FCD + idx] = fmaxf(v, 0.0f);
}

// ================= fallback machinery (round-10, proven bit-exact) =================
#define FMA8(BUF, KB)                                                                   \
    _Pragma("unroll")                                                                   \
    for (int u = 0; u < 8; u++) {                                                       \
        const float4* xv = (const float4*)&xs[(KB) + u][0];                             \
        float4 a0 = xv[0], a1 = xv[1];                                                  \
        float wx = BUF[u].x, wy = BUF[u].y;                                             \
        acc[0][0] = fmaf(a0.x, wx, acc[0][0]); acc[0][1] = fmaf(a0.x, wy, acc[0][1]);   \
        acc[1][0] = fmaf(a0.y, wx, acc[1][0]); acc[1][1] = fmaf(a0.y, wy, acc[1][1]);   \
        acc[2][0] = fmaf(a0.z, wx, acc[2][0]); acc[2][1] = fmaf(a0.z, wy, acc[2][1]);   \
        acc[3][0] = fmaf(a0.w, wx, acc[3][0]); acc[3][1] = fmaf(a0.w, wy, acc[3][1]);   \
        acc[4][0] = fmaf(a1.x, wx, acc[4][0]); acc[4][1] = fmaf(a1.x, wy, acc[4][1]);   \
        acc[5][0] = fmaf(a1.y, wx, acc[5][0]); acc[5][1] = fmaf(a1.y, wy, acc[5][1]);   \
        acc[6][0] = fmaf(a1.z, wx, acc[6][0]); acc[6][1] = fmaf(a1.z, wy, acc[6][1]);   \
        acc[7][0] = fmaf(a1.w, wx, acc[7][0]); acc[7][1] = fmaf(a1.w, wy, acc[7][1]);   \
    }

template <int KT>
__device__ __forceinline__ void fc_panel2(const float* __restrict__ wp,
                                          const float (*xs)[R1],
                                          float acc[R1][2]) {
    float2 wa[8], wb[8];
#pragma unroll
    for (int u = 0; u < 8; u++) wa[u] = *(const float2*)(wp + (size_t)u * FCD);
    for (int kk = 0; kk < KT; kk += 16) {
#pragma unroll
        for (int u = 0; u < 8; u++)
            wb[u] = *(const float2*)(wp + (size_t)(kk + 8 + u) * FCD);
        FMA8(wa, kk)
        if (kk + 16 < KT) {
#pragma unroll
            for (int u = 0; u < 8; u++)
                wa[u] = *(const float2*)(wp + (size_t)(kk + 16 + u) * FCD);
        }
        FMA8(wb, kk + 8)
    }
}

__global__ __launch_bounds__(256) void fc1_fallback(
    const float* __restrict__ p2, const float* __restrict__ p3,
    const float* __restrict__ p4, const float* __restrict__ p5,
    const int* __restrict__ prep, const float* __restrict__ W1,
    const float* __restrict__ b1, float* __restrict__ X1) {
    __shared__ float xs[KC][R1];
    __shared__ int s_ix[R1][7], s_iyW[R1][7], s_HW[R1];
    __shared__ const float* s_fp[R1];

    int tid = threadIdx.x;
    int c0 = blockIdx.x * 512 + tid * 2;
    int row0 = blockIdx.y * R1;

    if (tid < R1) {
        const int* pb = prep + (row0 + tid) * 20;
        int lvl = pb[0];
        s_fp[tid] = (lvl == 0 ? p2 : lvl == 1 ? p3 : lvl == 2 ? p4 : p5) + pb[1];
        s_HW[tid] = pb[2];
#pragma unroll
        for (int j = 0; j < 7; j++) { s_ix[tid][j] = pb[4 + j]; s_iyW[tid][j] = pb[12 + j]; }
    }

    float tot[R1][2];
#pragma unroll
    for (int r = 0; r < R1; r++) { tot[r][0] = 0.0f; tot[r][1] = 0.0f; }

    for (int k0 = 0; k0 < FCIN; k0 += KC) {
        int kt = FCIN - k0; if (kt > KC) kt = KC;
        __syncthreads();
        for (int e = tid; e < kt * R1; e += 256) {
            int kk = e >> 3;
            int r = e & 7;
            int k = k0 + kk;
            int c = k / 49;
            int p = k - c * 49;
            int gy = p / 7;
            int gx = p - gy * 7;
            xs[kk][r] = s_fp[r][c * s_HW[r] + s_iyW[r][gy] + s_ix[r][gx]];
        }
        __syncthreads();

        float acc[R1][2];
#pragma unroll
        for (int r = 0; r < R1; r++) { acc[r][0] = 0.0f; acc[r][1] = 0.0f; }

        const float* wp = W1 + (size_t)k0 * FCD + c0;
        if (kt == KC) fc_panel2<KC>(wp, xs, acc);
        else          fc_panel2<256>(wp, xs, acc);

#pragma unroll
        for (int r = 0; r < R1; r++) {
            tot[r][0] = __fadd_rn(tot[r][0], acc[r][0]);
            tot[r][1] = __fadd_rn(tot[r][1], acc[r][1]);
        }
    }
    float bv0 = b1[c0], bv1 = b1[c0 + 1];
#pragma unroll
    for (int r = 0; r < R1; r++) {
        float v0 = __fadd_rn(tot[r][0], bv0);
        float v1 = __fadd_rn(tot[r][1], bv1);
        X1[(size_t)(row0 + r) * FCD + c0]     = fmaxf(v0, 0.0f);
        X1[(size_t)(row0 + r) * FCD + c0 + 1] = fmaxf(v1, 0.0f);
    }
}

__global__ __launch_bounds__(256) void fc2_seq(
    const float* __restrict__ X1, const float* __restrict__ W2,
    const float* __restrict__ b2, float* __restrict__ X2) {
    __shared__ float xs[KC][R1];
    int tid = threadIdx.x;
    int c0 = blockIdx.x * 512 + tid * 2;
    int row0 = blockIdx.y * R1;

    float tot[R1][2];
#pragma unroll
    for (int r = 0; r < R1; r++) { tot[r][0] = 0.0f; tot[r][1] = 0.0f; }

    for (int k0 = 0; k0 < FCD; k0 += KC) {
        int kt = FCD - k0; if (kt > KC) kt = KC;
        __syncthreads();
        for (int e = tid; e < kt * R1; e += 256) {
            int kk = e >> 3;
            int r = e & 7;
            xs[kk][r] = X1[(size_t)(row0 + r) * FCD + k0 + kk];
        }
        __syncthreads();

        float acc[R1][2];
#pragma unroll
        for (int r = 0; r < R1; r++) { acc[r][0] = 0.0f; acc[r][1] = 0.0f; }

        const float* wp = W2 + (size_t)k0 * FCD + c0;
        if (kt == KC) fc_panel2<KC>(wp, xs, acc);
        else          fc_panel2<256>(wp, xs, acc);

#pragma unroll
        for (int r = 0; r < R1; r++) {
            tot[r][0] = __fadd_rn(tot[r][0], acc[r][0]);
            tot[r][1] = __fadd_rn(tot[r][1], acc[r][1]);
        }
    }
    float bv0 = b2[c0], bv1 = b2[c0 + 1];
#pragma unroll
    for (int r = 0; r < R1; r++) {
        float v0 = __fadd_rn(tot[r][0], bv0);
        float v1 = __fadd_rn(tot[r][1], bv1);
        X2[(size_t)(row0 + r) * FCD + c0]     = fmaxf(v0, 0.0f);
        X2[(size_t)(row0 + r) * FCD + c0 + 1] = fmaxf(v1, 0.0f);
    }
}

// ---------------- Heads, parallel: 8 boxes/block, 18 chains per box (q x panel) ----------------
__global__ __launch_bounds__(256) void heads_par(
    const float* __restrict__ X2,
    const float* __restrict__ Wc, const float* __restrict__ bc,
    const float* __restrict__ Wb, const float* __restrict__ bb_,
    const float* __restrict__ props, const int* __restrict__ img_sz,
    float* __restrict__ SC, float* __restrict__ BX) {
    int tid = threadIdx.x;
    int b0 = blockIdx.x * HB;
    __shared__ float xsh[HB][FCD];    // 32 KB
    __shared__ float wsh[6][FCD];     // 24 KB
    __shared__ float red[HB][6][3];
    __shared__ float lg[HB][6];

    for (int e = tid; e < HB * FCD; e += 256) {
        int r = e >> 10, k = e & (FCD - 1);
        xsh[r][k] = X2[(size_t)(b0 + r) * FCD + k];
    }
    for (int e = tid; e < 6 * FCD; e += 256) {
        int q = e / FCD, k = e - q * FCD;
        wsh[q][k] = (q < 2) ? Wc[k * 2 + q] : Wb[k * 4 + (q - 2)];
    }
    __syncthreads();

    int c = tid & 31, r = tid >> 5;
    if (c < 18) {
        int q = c / 3, p = c - q * 3;
        int k0 = p * KC;
        int kt = (p == 2) ? 256 : KC;
        float acc = 0.0f;
        for (int k = k0; k < k0 + kt; k++)
            acc = fmaf(xsh[r][k], wsh[q][k], acc);
        red[r][q][p] = acc;
    }
    __syncthreads();

    if (c < 6) {
        int q = c;
        float t = __fadd_rn(__fadd_rn(red[r][q][0], red[r][q][1]), red[r][q][2]);
        float bias = (q < 2) ? bc[q] : bb_[q - 2];
        lg[r][q] = __fadd_rn(t, bias);
    }
    __syncthreads();

    if (c == 0) {
        int b = b0 + r;
        float c0 = lg[r][0], c1 = lg[r][1];
        float mx = fmaxf(c0, c1);
        float e0 = (float)exp((double)__fsub_rn(c0, mx));
        float e1 = (float)exp((double)__fsub_rn(c1, mx));
        SC[b] = __fdiv_rn(e1, __fadd_rn(e0, e1));

        int n = b / NBOX;
        const float* pr = props + (size_t)b * 4;
        float x1 = pr[0], y1 = pr[1], x2 = pr[2], y2 = pr[3];
        float w = __fsub_rn(x2, x1), h = __fsub_rn(y2, y1);
        float cx = __fadd_rn(x1, __fmul_rn(0.5f, w));
        float cy = __fadd_rn(y1, __fmul_rn(0.5f, h));
        float dx = lg[r][2], dy = lg[r][3];
        float dw = fminf(lg[r][4], SCALE_CLAMP_F);
        float dh = fminf(lg[r][5], SCALE_CLAMP_F);
        float pcx = __fadd_rn(__fmul_rn(dx, w), cx);
        float pcy = __fadd_rn(__fmul_rn(dy, h), cy);
        float pw = __fmul_rn((float)exp((double)dw), w);
        float ph = __fmul_rn((float)exp((double)dh), h);
        float bx1 = __fsub_rn(pcx, __fmul_rn(0.5f, pw));
        float by1 = __fsub_rn(pcy, __fmul_rn(0.5f, ph));
        float bx2 = __fadd_rn(pcx, __fmul_rn(0.5f, pw));
        float by2 = __fadd_rn(pcy, __fmul_rn(0.5f, ph));
        float Hf = (float)img_sz[n * 2 + 0], Wf = (float)img_sz[n * 2 + 1];
        bx1 = fminf(fmaxf(bx1, 0.0f), Wf);
        by1 = fminf(fmaxf(by1, 0.0f), Hf);
        bx2 = fminf(fmaxf(bx2, 0.0f), Wf);
        by2 = fminf(fmaxf(by2, 0.0f), Hf);
        BX[(size_t)b * 4 + 0] = bx1;
        BX[(size_t)b * 4 + 1] = by1;
        BX[(size_t)b * 4 + 2] = bx2;
        BX[(size_t)b * 4 + 3] = by2;
    }
}

// ---------------- Bitmask NMS: parallel IoU mask, barrier-free greedy scan ----------------
// Dynamic LDS: mask[NW][1000] u64 (word-major), kmask[NW], pref[NW], sraw/ssort/bs/ord.
// IoU f32 expression sequence identical to rounds 8-17 (proven). Greedy semantics identical.
__global__ __launch_bounds__(1024) void nms_bitmask(const float* __restrict__ SC,
                                                    const float* __restrict__ BX,
                                                    float* __restrict__ out) {
    extern __shared__ unsigned long long dsm[];
    unsigned long long* mask = dsm;                       // NW * 1000
    unsigned long long* kmask = dsm + NW * NBOX;          // NW
    unsigned int* pref = (unsigned int*)(kmask + NW);     // NW
    float* sraw = (float*)(pref + NW);                    // 1000
    float* ssort = sraw + NBOX;                           // 1000
    float* bs = ssort + NBOX;                             // 1000*4
    int* ord = (int*)(bs + NBOX * 4);                     // 1000

    int n = blockIdx.x;
    int tid = threadIdx.x;

    for (int j = tid; j < NBOX; j += 1024) sraw[j] = SC[n * NBOX + j];
    __syncthreads();

    // stable descending rank (ties -> lower original index)
    if (tid < NBOX) {
        float sj = sraw[tid];
        int r = 0;
        for (int k = 0; k < NBOX; k++) {
            float sk = sraw[k];
            r += (sk > sj) || (sk == sj && k < tid);
        }
        ord[r] = tid;
        ssort[r] = sj;
#pragma unroll
        for (int k = 0; k < 4; k++) bs[r * 4 + k] = BX[((size_t)n * NBOX + tid) * 4 + k];
    }
    __syncthreads();

    // init keep bits from score threshold
    if (tid < NW) {
        unsigned long long m = 0;
        for (int b = 0; b < 64; b++) {
            int r = tid * 64 + b;
            if (r < NBOX && ssort[r] > 0.05f) m |= 1ull << b;
        }
        kmask[tid] = m;
    }

    // build suppression mask: row i, bit j set iff j>i && IoU(i,j)>0.5 (exact f32 ops)
    if (tid < NBOX) {
        int i = tid;
        float ax1 = bs[i * 4 + 0], ay1 = bs[i * 4 + 1], ax2 = bs[i * 4 + 2], ay2 = bs[i * 4 + 3];
        float areaA = __fmul_rn(__fsub_rn(ax2, ax1), __fsub_rn(ay2, ay1));
        for (int w = 0; w < NW; w++) {
            unsigned long long m = 0;
            int jbase = w * 64;
            for (int b = 0; b < 64; b++) {
                int j = jbase + b;
                if (j < NBOX && j > i) {
                    float bx1 = bs[j * 4 + 0], by1 = bs[j * 4 + 1];
                    float bx2 = bs[j * 4 + 2], by2 = bs[j * 4 + 3];
                    float areaB = __fmul_rn(__fsub_rn(bx2, bx1), __fsub_rn(by2, by1));
                    float ix1 = fmaxf(ax1, bx1), iy1 = fmaxf(ay1, by1);
                    float ix2 = fminf(ax2, bx2), iy2 = fminf(ay2, by2);
                    float iw = fmaxf(__fsub_rn(ix2, ix1), 0.0f);
                    float ih = fmaxf(__fsub_rn(iy2, iy1), 0.0f);
                    float inter = __fmul_rn(iw, ih);
                    float denom = fmaxf(__fsub_rn(__fadd_rn(areaA, areaB), inter), 1e-9f);
                    if (__fdiv_rn(inter, denom) > 0.5f) m |= 1ull << b;
                }
            }
            mask[(size_t)w * NBOX + i] = m;   // word-major: conflict-free writes
        }
    }
    __syncthreads();

    // barrier-free greedy scan on wave 0: lane q owns keep-word q
    if (tid < 64) {
        int lane = tid;
        unsigned long long myw = (lane < NW) ? kmask[lane] : 0ull;
        for (int i = 0; i < NBOX; i++) {
            unsigned long long cw = __shfl(myw, i >> 6);
            if ((cw >> (i & 63)) & 1ull) {
                if (lane < NW) myw &= ~mask[(size_t)lane * NBOX + i];
            }
        }
        if (lane < NW) kmask[lane] = myw;
    }
    __syncthreads();

    // prefix popcounts for top-100 cumsum
    if (tid == 0) {
        unsigned int c = 0;
        for (int w = 0; w < NW; w++) { pref[w] = c; c += (unsigned int)__popcll(kmask[w]); }
    }
    __syncthreads();

    float* boxes_o = out;
    float* scores_o = out + (size_t)NIMG * NBOX * 4;
    float* keep_o = scores_o + (size_t)NIMG * NBOX;
    float* ord_o = keep_o + (size_t)NIMG * NBOX;
    if (tid < NBOX) {
        int r = tid;
        int w = r >> 6, b = r & 63;
        unsigned long long kw = kmask[w];
        int bit = (int)((kw >> b) & 1ull);
        unsigned long long lowmask = b ? ((1ull << b) - 1ull) : 0ull;
        int csum = (int)pref[w] + (int)__popcll(kw & lowmask) + bit;   // inclusive cumsum
        int kfin = (bit && csum <= TOPK) ? 1 : 0;
#pragma unroll
        for (int k = 0; k < 4; k++)
            boxes_o[((size_t)n * NBOX + r) * 4 + k] = bs[r * 4 + k];
        scores_o[n * NBOX + r] = ssort[r];
        keep_o[n * NBOX + r] = (float)kfin;
        ord_o[n * NBOX + r] = (float)ord[r];
    }
}

extern "C" void kernel_launch(void* const* d_in, const int* in_sizes, int n_in,
                              void* d_out, int out_size, void* d_ws, size_t ws_size,
                              hipStream_t stream) {
    const float* p2 = (const float*)d_in[0];
    const float* p3 = (const float*)d_in[1];
    const float* p4 = (const float*)d_in[2];
    const float* p5 = (const float*)d_in[3];
    const float* props = (const float*)d_in[4];
    const int* img = (const int*)d_in[5];
    const float* W1 = (const float*)d_in[6];
    const float* b1 = (const float*)d_in[7];
    const float* W2 = (const float*)d_in[8];
    const float* b2 = (const float*)d_in[9];
    const float* Wc = (const float*)d_in[10];
    const float* bc = (const float*)d_in[11];
    const float* Wb = (const float*)d_in[12];
    const float* bb = (const float*)d_in[13];

    float* X1 = (float*)d_ws;
    float* X2 = X1 + (size_t)2000 * FCD;
    float* SCf = X2 + (size_t)2000 * FCD;
    float* BXf = SCf + 2000;
    int* prep = (int*)(BXf + 8000);
    float* part = (float*)(prep + 2000 * 20);
    size_t used = (size_t)((char*)part - (char*)d_ws);
    size_t avail = ws_size > used ? ws_size - used : 0;

    prep_kernel<<<(NIMG * NBOX + 255) / 256, 256, 0, stream>>>(props, prep);

    // fc1: single sweep preferred (720 us proven optimum)
    int gmax = 0;
    const int cand[4] = {125, 63, 32, 16};
    for (int i = 0; i < 4; i++) {
        size_t need = (size_t)NPANEL * cand[i] * RB * FCD * sizeof(float);
        if (need <= avail) { gmax = cand[i]; break; }
    }

    if (gmax > 0) {
        for (int g0 = 0; g0 < NGROUP; g0 += gmax) {
            int gs = NGROUP - g0; if (gs > gmax) gs = gmax;
            dim3 gA(gs, NPANEL);
            fc1_panel<<<gA, 256, 0, stream>>>(p2, p3, p4, p5, prep, W1, part, g0, gs);
            int nelem = gs * RB * FCD;
            fold_bias_relu<<<(nelem + 255) / 256, 256, 0, stream>>>(part, b1, X1,
                                                                    g0 * RB, gs * RB, NPANEL);
        }
    } else {
        dim3 gfc(2, (NIMG * NBOX) / R1);
        fc1_fallback<<<gfc, 256, 0, stream>>>(p2, p3, p4, p5, prep, W1, b1, X1);
    }

    // fc2: panel-parallel if partial buffer fits, else proven fc2_seq
    size_t need2 = (size_t)NP2 * NIMG * NBOX * FCD * sizeof(float);
    if (need2 <= avail) {
        dim3 g2(NIMG * NBOX / RB2, NP2);           // (250, 3)
        fc2_panel<<<g2, 256, 0, stream>>>(X1, W2, part);
        int nelem2 = NIMG * NBOX * FCD;
        fold_bias_relu<<<(nelem2 + 255) / 256, 256, 0, stream>>>(part, b2, X2,
                                                                 0, NIMG * NBOX, NP2);
    } else {
        dim3 gfc2(2, (NIMG * NBOX) / R1);
        fc2_seq<<<gfc2, 256, 0, stream>>>(X1, W2, b2, X2);
    }

    heads_par<<<NIMG * NBOX / HB, 256, 0, stream>>>(X2, Wc, bc, Wb, bb, props, img, SCf, BXf);

    // dynamic LDS: mask 128,000 + kmask 128 + pref 64 + sraw/ssort/bs/ord 28,000 = 156,192 B
    size_t nms_lds = (size_t)NW * NBOX * 8 + NW * 8 + NW * 4
                   + (size_t)(NBOX + NBOX + NBOX * 4) * 4 + NBOX * 4;
    nms_bitmask<<<NIMG, 1024, nms_lds, stream>>>(SCf, BXf, (float*)d_out);
}

// Round 19
// 1089.861 us; speedup vs baseline: 1.1457x; 1.0230x over previous
//
#include <hip/hip_runtime.h>
#include <math.h>

#define NBOX 1000
#define NIMG 2
#define CCH 256
#define FCIN 12544   // 256*7*7
#define FCD 1024
#define TOPK 100
#define SCALE_CLAMP_F ((float)4.135166556742356)  // f32(np.log(1000/16))
#define KC 384       // OpenBLAS SGEMM_DEFAULT_Q -- FROZEN numerics invariant
#define NPANEL 33    // 12544 = 32*384 + 256
#define RB 16        // rows per fc1 panel-block
#define NGROUP 125   // 2000/16
#define CHUNK 128    // LDS staging chunk (divides 384 and 256)
#define RB2 8        // rows per fc2 panel-block
#define NP2 3        // fc2 panels: 384,384,256
#define R1 8         // rows per block, fallback path
#define HB 8         // boxes per heads block
#define NW 16        // u64 words covering 1000 rank bits

// ---------------- Prep: per-box level + gather indices (strict f32, numpy op order) ----------------
__global__ void prep_kernel(const float* __restrict__ props, int* __restrict__ prep) {
    int b = blockIdx.x * blockDim.x + threadIdx.x;
    if (b >= NIMG * NBOX) return;
    int n = b / NBOX;
    const float* pr = props + (size_t)b * 4;
    float x1 = pr[0], y1 = pr[1], x2 = pr[2], y2 = pr[3];

    float w = __fsub_rn(x2, x1), h = __fsub_rn(y2, y1);
    float s = sqrtf(fmaxf(__fmul_rn(w, h), 1e-6f));
    float l2 = (float)log2((double)__fadd_rn(__fdiv_rn(s, 224.0f), 1e-8f));
    float lv = floorf(__fadd_rn(4.0f, l2));
    lv = fminf(fmaxf(lv, 2.0f), 5.0f);
    int lvl = (int)lv - 2;

    int H, W; float scale;
    if (lvl == 0)      { H = 200; W = 304; scale = 0.25f; }
    else if (lvl == 1) { H = 100; W = 152; scale = 0.125f; }
    else if (lvl == 2) { H = 50;  W = 76;  scale = 0.0625f; }
    else               { H = 25;  W = 38;  scale = 0.03125f; }

    float xs1 = __fmul_rn(x1, scale), ys1 = __fmul_rn(y1, scale);
    float xs2 = __fmul_rn(x2, scale), ys2 = __fmul_rn(y2, scale);
    float bw = __fdiv_rn(fmaxf(__fsub_rn(xs2, xs1), 1.0f), 7.0f);
    float bh = __fdiv_rn(fmaxf(__fsub_rn(ys2, ys1), 1.0f), 7.0f);

    int* pb = prep + b * 20;
    pb[0] = lvl;
    pb[1] = n * CCH * H * W;
    pb[2] = H * W;
#pragma unroll
    for (int i = 0; i < 7; i++) {
        float cs = (float)i + 0.5f;
        float gx = __fadd_rn(xs1, __fmul_rn(cs, bw));
        float gy = __fadd_rn(ys1, __fmul_rn(cs, bh));
        int vx = (int)gx;
        int vy = (int)gy;
        vx = vx < 0 ? 0 : (vx > W - 1 ? W - 1 : vx);
        vy = vy < 0 ? 0 : (vy > H - 1 ? H - 1 : vy);
        pb[4 + i] = vx;
        pb[12 + i] = vy * W;
    }
}

// ================= Panel-parallel FC1 (r13 structure + 4-deep W prefetch) =================
// Only change vs round 18: k-loop unrolled by 4 with four named W registers -- loads go
// 2-3 k ahead; FMA order remains strictly ascending k (bit-exact chain preserved).
#define FMASTEP(KB, WV)                                               \
    {                                                                 \
        const float4* xv = (const float4*)&xs[(KB)][0];               \
        float4 a0 = xv[0], a1 = xv[1], a2 = xv[2], a3 = xv[3];        \
        float xr[16] = {a0.x, a0.y, a0.z, a0.w, a1.x, a1.y, a1.z, a1.w, \
                        a2.x, a2.y, a2.z, a2.w, a3.x, a3.y, a3.z, a3.w}; \
        _Pragma("unroll")                                             \
        for (int r = 0; r < RB; r++) {                                \
            acc[r][0] = fmaf(xr[r], WV.x, acc[r][0]);                 \
            acc[r][1] = fmaf(xr[r], WV.y, acc[r][1]);                 \
            acc[r][2] = fmaf(xr[r], WV.z, acc[r][2]);                 \
            acc[r][3] = fmaf(xr[r], WV.w, acc[r][3]);                 \
        }                                                             \
    }

__global__ __launch_bounds__(256, 4) void fc1_panel(
    const float* __restrict__ p2, const float* __restrict__ p3,
    const float* __restrict__ p4, const float* __restrict__ p5,
    const int* __restrict__ prep, const float* __restrict__ W1,
    float* __restrict__ part, int g0, int gs) {
    __shared__ float xs[CHUNK][RB];
    __shared__ int s_ix[RB][7], s_iyW[RB][7], s_HW[RB];
    __shared__ const float* s_fp[RB];

    int tid = threadIdx.x;
    int gy = blockIdx.x;
    int p = blockIdx.y;
    int row0 = (g0 + gy) * RB;
    int k0 = p * KC;
    int kt = (p == NPANEL - 1) ? 256 : KC;

    if (tid < RB) {
        const int* pb = prep + (row0 + tid) * 20;
        int lvl = pb[0];
        s_fp[tid] = (lvl == 0 ? p2 : lvl == 1 ? p3 : lvl == 2 ? p4 : p5) + pb[1];
        s_HW[tid] = pb[2];
#pragma unroll
        for (int j = 0; j < 7; j++) { s_ix[tid][j] = pb[4 + j]; s_iyW[tid][j] = pb[12 + j]; }
    }
    __syncthreads();

    float acc[RB][4];
#pragma unroll
    for (int r = 0; r < RB; r++)
#pragma unroll
        for (int j = 0; j < 4; j++) acc[r][j] = 0.0f;

    const float* wp = W1 + (size_t)k0 * FCD + tid * 4;

    for (int ck = 0; ck < kt; ck += CHUNK) {
        for (int e = tid; e < CHUNK * RB; e += 256) {
            int kk = e >> 4;
            int r = e & 15;
            int k = k0 + ck + kk;
            int c = k / 49;
            int pp = k - c * 49;
            int gyy = pp / 7;
            int gxx = pp - gyy * 7;
            xs[kk][r] = s_fp[r][c * s_HW[r] + s_iyW[r][gyy] + s_ix[r][gxx]];
        }
        __syncthreads();

        const float* wc = wp + (size_t)ck * FCD;
        float4 wA = *(const float4*)(wc);
        float4 wB = *(const float4*)(wc + (size_t)1 * FCD);
        for (int kk = 0; kk < CHUNK; kk += 4) {
            float4 wC = *(const float4*)(wc + (size_t)(kk + 2) * FCD);
            float4 wD = *(const float4*)(wc + (size_t)(kk + 3) * FCD);
            FMASTEP(kk, wA)                   // k ascending: chain order preserved
            FMASTEP(kk + 1, wB)
            if (kk + 4 < CHUNK) {
                wA = *(const float4*)(wc + (size_t)(kk + 4) * FCD);
                wB = *(const float4*)(wc + (size_t)(kk + 5) * FCD);
            }
            FMASTEP(kk + 2, wC)
            FMASTEP(kk + 3, wD)
        }
        __syncthreads();
    }

    size_t pstride = (size_t)gs * RB * FCD;
    float* po = part + (size_t)p * pstride + ((size_t)gy * RB) * FCD + tid * 4;
#pragma unroll
    for (int r = 0; r < RB; r++) {
        float4 v = make_float4(acc[r][0], acc[r][1], acc[r][2], acc[r][3]);
        *(float4*)(po + (size_t)r * FCD) = v;
    }
}

// ================= Panel-parallel FC2 =================
__global__ __launch_bounds__(256, 4) void fc2_panel(
    const float* __restrict__ X1, const float* __restrict__ W2,
    float* __restrict__ part) {
    __shared__ float xs2[CHUNK][RB2];
    int tid = threadIdx.x;
    int gy = blockIdx.x;
    int p = blockIdx.y;
    int row0 = gy * RB2;
    int k0 = p * KC;
    int kt = (p == NP2 - 1) ? 256 : KC;

    float acc[RB2][4];
#pragma unroll
    for (int r = 0; r < RB2; r++)
#pragma unroll
        for (int j = 0; j < 4; j++) acc[r][j] = 0.0f;

    const float* wp = W2 + (size_t)k0 * FCD + tid * 4;

    for (int ck = 0; ck < kt; ck += CHUNK) {
        for (int e = tid; e < CHUNK * RB2; e += 256) {
            int kk = e >> 3;
            int r = e & 7;
            xs2[kk][r] = X1[(size_t)(row0 + r) * FCD + k0 + ck + kk];
        }
        __syncthreads();

        const float* wc = wp + (size_t)ck * FCD;
        float4 wA = *(const float4*)wc;
        for (int kk = 0; kk < CHUNK; kk += 2) {
            float4 wB = *(const float4*)(wc + (size_t)(kk + 1) * FCD);
            {
                const float4* xv = (const float4*)&xs2[kk][0];
                float4 a0 = xv[0], a1 = xv[1];
                float xr[8] = {a0.x, a0.y, a0.z, a0.w, a1.x, a1.y, a1.z, a1.w};
#pragma unroll
                for (int r = 0; r < RB2; r++) {
                    acc[r][0] = fmaf(xr[r], wA.x, acc[r][0]);
                    acc[r][1] = fmaf(xr[r], wA.y, acc[r][1]);
                    acc[r][2] = fmaf(xr[r], wA.z, acc[r][2]);
                    acc[r][3] = fmaf(xr[r], wA.w, acc[r][3]);
                }
            }
            if (kk + 2 < CHUNK) wA = *(const float4*)(wc + (size_t)(kk + 2) * FCD);
            {
                const float4* xv = (const float4*)&xs2[kk + 1][0];
                float4 a0 = xv[0], a1 = xv[1];
                float xr[8] = {a0.x, a0.y, a0.z, a0.w, a1.x, a1.y, a1.z, a1.w};
#pragma unroll
                for (int r = 0; r < RB2; r++) {
                    acc[r][0] = fmaf(xr[r], wB.x, acc[r][0]);
                    acc[r][1] = fmaf(xr[r], wB.y, acc[r][1]);
                    acc[r][2] = fmaf(xr[r], wB.z, acc[r][2]);
                    acc[r][3] = fmaf(xr[r], wB.w, acc[r][3]);
                }
            }
        }
        __syncthreads();
    }

    size_t pstride = (size_t)NIMG * NBOX * FCD;
    float* po = part + (size_t)p * pstride + ((size_t)row0) * FCD + tid * 4;
#pragma unroll
    for (int r = 0; r < RB2; r++) {
        float4 v = make_float4(acc[r][0], acc[r][1], acc[r][2], acc[r][3]);
        *(float4*)(po + (size_t)r * FCD) = v;
    }
}

// Ordered left-fold over panel chains + bias + ReLU. Exact OpenBLAS panel fold.
__global__ void fold_bias_relu(const float* __restrict__ part, const float* __restrict__ bias,
                               float* __restrict__ Xout, int row_base, int rows_s, int npanel) {
    int idx = blockIdx.x * 256 + threadIdx.x;
    if (idx >= rows_s * FCD) return;
    size_t stride = (size_t)rows_s * FCD;
    float tot = part[idx];
    for (int p = 1; p < npanel; p++)
        tot = __fadd_rn(tot, part[(size_t)p * stride + idx]);
    int c = idx & (FCD - 1);
    float v = __fadd_rn(tot, bias[c]);
    Xout[(size_t)row_base * FCD + idx] = fmaxf(v, 0.0f);
}

// ================= fallback machinery (round-10, proven bit-exact) =================
#define FMA8(BUF, KB)                                                                   \
    _Pragma("unroll")                                                                   \
    for (int u = 0; u < 8; u++) {                                                       \
        const float4* xv = (const float4*)&xs[(KB) + u][0];                             \
        float4 a0 = xv[0], a1 = xv[1];                                                  \
        float wx = BUF[u].x, wy = BUF[u].y;                                             \
        acc[0][0] = fmaf(a0.x, wx, acc[0][0]); acc[0][1] = fmaf(a0.x, wy, acc[0][1]);   \
        acc[1][0] = fmaf(a0.y, wx, acc[1][0]); acc[1][1] = fmaf(a0.y, wy, acc[1][1]);   \
        acc[2][0] = fmaf(a0.z, wx, acc[2][0]); acc[2][1] = fmaf(a0.z, wy, acc[2][1]);   \
        acc[3][0] = fmaf(a0.w, wx, acc[3][0]); acc[3][1] = fmaf(a0.w, wy, acc[3][1]);   \
        acc[4][0] = fmaf(a1.x, wx, acc[4][0]); acc[4][1] = fmaf(a1.x, wy, acc[4][1]);   \
        acc[5][0] = fmaf(a1.y, wx, acc[5][0]); acc[5][1] = fmaf(a1.y, wy, acc[5][1]);   \
        acc[6][0] = fmaf(a1.z, wx, acc[6][0]); acc[6][1] = fmaf(a1.z, wy, acc[6][1]);   \
        acc[7][0] = fmaf(a1.w, wx, acc[7][0]); acc[7][1] = fmaf(a1.w, wy, acc[7][1]);   \
    }

template <int KT>
__device__ __forceinline__ void fc_panel2(const float* __restrict__ wp,
                                          const float (*xs)[R1],
                                          float acc[R1][2]) {
    float2 wa[8], wb[8];
#pragma unroll
    for (int u = 0; u < 8; u++) wa[u] = *(const float2*)(wp + (size_t)u * FCD);
    for (int kk = 0; kk < KT; kk += 16) {
#pragma unroll
        for (int u = 0; u < 8; u++)
            wb[u] = *(const float2*)(wp + (size_t)(kk + 8 + u) * FCD);
        FMA8(wa, kk)
        if (kk + 16 < KT) {
#pragma unroll
            for (int u = 0; u < 8; u++)
                wa[u] = *(const float2*)(wp + (size_t)(kk + 16 + u) * FCD);
        }
        FMA8(wb, kk + 8)
    }
}

__global__ __launch_bounds__(256) void fc1_fallback(
    const float* __restrict__ p2, const float* __restrict__ p3,
    const float* __restrict__ p4, const float* __restrict__ p5,
    const int* __restrict__ prep, const float* __restrict__ W1,
    const float* __restrict__ b1, float* __restrict__ X1) {
    __shared__ float xs[KC][R1];
    __shared__ int s_ix[R1][7], s_iyW[R1][7], s_HW[R1];
    __shared__ const float* s_fp[R1];

    int tid = threadIdx.x;
    int c0 = blockIdx.x * 512 + tid * 2;
    int row0 = blockIdx.y * R1;

    if (tid < R1) {
        const int* pb = prep + (row0 + tid) * 20;
        int lvl = pb[0];
        s_fp[tid] = (lvl == 0 ? p2 : lvl == 1 ? p3 : lvl == 2 ? p4 : p5) + pb[1];
        s_HW[tid] = pb[2];
#pragma unroll
        for (int j = 0; j < 7; j++) { s_ix[tid][j] = pb[4 + j]; s_iyW[tid][j] = pb[12 + j]; }
    }

    float tot[R1][2];
#pragma unroll
    for (int r = 0; r < R1; r++) { tot[r][0] = 0.0f; tot[r][1] = 0.0f; }

    for (int k0 = 0; k0 < FCIN; k0 += KC) {
        int kt = FCIN - k0; if (kt > KC) kt = KC;
        __syncthreads();
        for (int e = tid; e < kt * R1; e += 256) {
            int kk = e >> 3;
            int r = e & 7;
            int k = k0 + kk;
            int c = k / 49;
            int p = k - c * 49;
            int gy = p / 7;
            int gx = p - gy * 7;
            xs[kk][r] = s_fp[r][c * s_HW[r] + s_iyW[r][gy] + s_ix[r][gx]];
        }
        __syncthreads();

        float acc[R1][2];
#pragma unroll
        for (int r = 0; r < R1; r++) { acc[r][0] = 0.0f; acc[r][1] = 0.0f; }

        const float* wp = W1 + (size_t)k0 * FCD + c0;
        if (kt == KC) fc_panel2<KC>(wp, xs, acc);
        else          fc_panel2<256>(wp, xs, acc);

#pragma unroll
        for (int r = 0; r < R1; r++) {
            tot[r][0] = __fadd_rn(tot[r][0], acc[r][0]);
            tot[r][1] = __fadd_rn(tot[r][1], acc[r][1]);
        }
    }
    float bv0 = b1[c0], bv1 = b1[c0 + 1];
#pragma unroll
    for (int r = 0; r < R1; r++) {
        float v0 = __fadd_rn(tot[r][0], bv0);
        float v1 = __fadd_rn(tot[r][1], bv1);
        X1[(size_t)(row0 + r) * FCD + c0]     = fmaxf(v0, 0.0f);
        X1[(size_t)(row0 + r) * FCD + c0 + 1] = fmaxf(v1, 0.0f);
    }
}

__global__ __launch_bounds__(256) void fc2_seq(
    const float* __restrict__ X1, const float* __restrict__ W2,
    const float* __restrict__ b2, float* __restrict__ X2) {
    __shared__ float xs[KC][R1];
    int tid = threadIdx.x;
    int c0 = blockIdx.x * 512 + tid * 2;
    int row0 = blockIdx.y * R1;

    float tot[R1][2];
#pragma unroll
    for (int r = 0; r < R1; r++) { tot[r][0] = 0.0f; tot[r][1] = 0.0f; }

    for (int k0 = 0; k0 < FCD; k0 += KC) {
        int kt = FCD - k0; if (kt > KC) kt = KC;
        __syncthreads();
        for (int e = tid; e < kt * R1; e += 256) {
            int kk = e >> 3;
            int r = e & 7;
            xs[kk][r] = X1[(size_t)(row0 + r) * FCD + k0 + kk];
        }
        __syncthreads();

        float acc[R1][2];
#pragma unroll
        for (int r = 0; r < R1; r++) { acc[r][0] = 0.0f; acc[r][1] = 0.0f; }

        const float* wp = W2 + (size_t)k0 * FCD + c0;
        if (kt == KC) fc_panel2<KC>(wp, xs, acc);
        else          fc_panel2<256>(wp, xs, acc);

#pragma unroll
        for (int r = 0; r < R1; r++) {
            tot[r][0] = __fadd_rn(tot[r][0], acc[r][0]);
            tot[r][1] = __fadd_rn(tot[r][1], acc[r][1]);
        }
    }
    float bv0 = b2[c0], bv1 = b2[c0 + 1];
#pragma unroll
    for (int r = 0; r < R1; r++) {
        float v0 = __fadd_rn(tot[r][0], bv0);
        float v1 = __fadd_rn(tot[r][1], bv1);
        X2[(size_t)(row0 + r) * FCD + c0]     = fmaxf(v0, 0.0f);
        X2[(size_t)(row0 + r) * FCD + c0 + 1] = fmaxf(v1, 0.0f);
    }
}

// ---------------- Heads, parallel: 8 boxes/block, 18 chains per box (q x panel) ----------------
__global__ __launch_bounds__(256) void heads_par(
    const float* __restrict__ X2,
    const float* __restrict__ Wc, const float* __restrict__ bc,
    const float* __restrict__ Wb, const float* __restrict__ bb_,
    const float* __restrict__ props, const int* __restrict__ img_sz,
    float* __restrict__ SC, float* __restrict__ BX) {
    int tid = threadIdx.x;
    int b0 = blockIdx.x * HB;
    __shared__ float xsh[HB][FCD];    // 32 KB
    __shared__ float wsh[6][FCD];     // 24 KB
    __shared__ float red[HB][6][3];
    __shared__ float lg[HB][6];

    for (int e = tid; e < HB * FCD; e += 256) {
        int r = e >> 10, k = e & (FCD - 1);
        xsh[r][k] = X2[(size_t)(b0 + r) * FCD + k];
    }
    for (int e = tid; e < 6 * FCD; e += 256) {
        int q = e / FCD, k = e - q * FCD;
        wsh[q][k] = (q < 2) ? Wc[k * 2 + q] : Wb[k * 4 + (q - 2)];
    }
    __syncthreads();

    int c = tid & 31, r = tid >> 5;
    if (c < 18) {
        int q = c / 3, p = c - q * 3;
        int k0 = p * KC;
        int kt = (p == 2) ? 256 : KC;
        float acc = 0.0f;
        for (int k = k0; k < k0 + kt; k++)
            acc = fmaf(xsh[r][k], wsh[q][k], acc);
        red[r][q][p] = acc;
    }
    __syncthreads();

    if (c < 6) {
        int q = c;
        float t = __fadd_rn(__fadd_rn(red[r][q][0], red[r][q][1]), red[r][q][2]);
        float bias = (q < 2) ? bc[q] : bb_[q - 2];
        lg[r][q] = __fadd_rn(t, bias);
    }
    __syncthreads();

    if (c == 0) {
        int b = b0 + r;
        float c0 = lg[r][0], c1 = lg[r][1];
        float mx = fmaxf(c0, c1);
        float e0 = (float)exp((double)__fsub_rn(c0, mx));
        float e1 = (float)exp((double)__fsub_rn(c1, mx));
        SC[b] = __fdiv_rn(e1, __fadd_rn(e0, e1));

        int n = b / NBOX;
        const float* pr = props + (size_t)b * 4;
        float x1 = pr[0], y1 = pr[1], x2 = pr[2], y2 = pr[3];
        float w = __fsub_rn(x2, x1), h = __fsub_rn(y2, y1);
        float cx = __fadd_rn(x1, __fmul_rn(0.5f, w));
        float cy = __fadd_rn(y1, __fmul_rn(0.5f, h));
        float dx = lg[r][2], dy = lg[r][3];
        float dw = fminf(lg[r][4], SCALE_CLAMP_F);
        float dh = fminf(lg[r][5], SCALE_CLAMP_F);
        float pcx = __fadd_rn(__fmul_rn(dx, w), cx);
        float pcy = __fadd_rn(__fmul_rn(dy, h), cy);
        float pw = __fmul_rn((float)exp((double)dw), w);
        float ph = __fmul_rn((float)exp((double)dh), h);
        float bx1 = __fsub_rn(pcx, __fmul_rn(0.5f, pw));
        float by1 = __fsub_rn(pcy, __fmul_rn(0.5f, ph));
        float bx2 = __fadd_rn(pcx, __fmul_rn(0.5f, pw));
        float by2 = __fadd_rn(pcy, __fmul_rn(0.5f, ph));
        float Hf = (float)img_sz[n * 2 + 0], Wf = (float)img_sz[n * 2 + 1];
        bx1 = fminf(fmaxf(bx1, 0.0f), Wf);
        by1 = fminf(fmaxf(by1, 0.0f), Hf);
        bx2 = fminf(fmaxf(bx2, 0.0f), Wf);
        by2 = fminf(fmaxf(by2, 0.0f), Hf);
        BX[(size_t)b * 4 + 0] = bx1;
        BX[(size_t)b * 4 + 1] = by1;
        BX[(size_t)b * 4 + 2] = bx2;
        BX[(size_t)b * 4 + 3] = by2;
    }
}

// ---------------- Bitmask NMS: parallel IoU mask, barrier-free greedy scan ----------------
__global__ __launch_bounds__(1024) void nms_bitmask(const float* __restrict__ SC,
                                                    const float* __restrict__ BX,
                                                    float* __restrict__ out) {
    extern __shared__ unsigned long long dsm[];
    unsigned long long* mask = dsm;                       // NW * 1000
    unsigned long long* kmask = dsm + NW * NBOX;          // NW
    unsigned int* pref = (unsigned int*)(kmask + NW);     // NW
    float* sraw = (float*)(pref + NW);                    // 1000
    float* ssort = sraw + NBOX;                           // 1000
    float* bs = ssort + NBOX;                             // 1000*4
    int* ord = (int*)(bs + NBOX * 4);                     // 1000

    int n = blockIdx.x;
    int tid = threadIdx.x;

    for (int j = tid; j < NBOX; j += 1024) sraw[j] = SC[n * NBOX + j];
    __syncthreads();

    if (tid < NBOX) {
        float sj = sraw[tid];
        int r = 0;
        for (int k = 0; k < NBOX; k++) {
            float sk = sraw[k];
            r += (sk > sj) || (sk == sj && k < tid);
        }
        ord[r] = tid;
        ssort[r] = sj;
#pragma unroll
        for (int k = 0; k < 4; k++) bs[r * 4 + k] = BX[((size_t)n * NBOX + tid) * 4 + k];
    }
    __syncthreads();

    if (tid < NW) {
        unsigned long long m = 0;
        for (int b = 0; b < 64; b++) {
            int r = tid * 64 + b;
            if (r < NBOX && ssort[r] > 0.05f) m |= 1ull << b;
        }
        kmask[tid] = m;
    }

    if (tid < NBOX) {
        int i = tid;
        float ax1 = bs[i * 4 + 0], ay1 = bs[i * 4 + 1], ax2 = bs[i * 4 + 2], ay2 = bs[i * 4 + 3];
        float areaA = __fmul_rn(__fsub_rn(ax2, ax1), __fsub_rn(ay2, ay1));
        for (int w = 0; w < NW; w++) {
            unsigned long long m = 0;
            int jbase = w * 64;
            for (int b = 0; b < 64; b++) {
                int j = jbase + b;
                if (j < NBOX && j > i) {
                    float bx1 = bs[j * 4 + 0], by1 = bs[j * 4 + 1];
                    float bx2 = bs[j * 4 + 2], by2 = bs[j * 4 + 3];
                    float areaB = __fmul_rn(__fsub_rn(bx2, bx1), __fsub_rn(by2, by1));
                    float ix1 = fmaxf(ax1, bx1), iy1 = fmaxf(ay1, by1);
                    float ix2 = fminf(ax2, bx2), iy2 = fminf(ay2, by2);
                    float iw = fmaxf(__fsub_rn(ix2, ix1), 0.0f);
                    float ih = fmaxf(__fsub_rn(iy2, iy1), 0.0f);
                    float inter = __fmul_rn(iw, ih);
                    float denom = fmaxf(__fsub_rn(__fadd_rn(areaA, areaB), inter), 1e-9f);
                    if (__fdiv_rn(inter, denom) > 0.5f) m |= 1ull << b;
                }
            }
            mask[(size_t)w * NBOX + i] = m;
        }
    }
    __syncthreads();

    if (tid < 64) {
        int lane = tid;
        unsigned long long myw = (lane < NW) ? kmask[lane] : 0ull;
        for (int i = 0; i < NBOX; i++) {
            unsigned long long cw = __shfl(myw, i >> 6);
            if ((cw >> (i & 63)) & 1ull) {
                if (lane < NW) myw &= ~mask[(size_t)lane * NBOX + i];
            }
        }
        if (lane < NW) kmask[lane] = myw;
    }
    __syncthreads();

    if (tid == 0) {
        unsigned int c = 0;
        for (int w = 0; w < NW; w++) { pref[w] = c; c += (unsigned int)__popcll(kmask[w]); }
    }
    __syncthreads();

    float* boxes_o = out;
    float* scores_o = out + (size_t)NIMG * NBOX * 4;
    float* keep_o = scores_o + (size_t)NIMG * NBOX;
    float* ord_o = keep_o + (size_t)NIMG * NBOX;
    if (tid < NBOX) {
        int r = tid;
        int w = r >> 6, b = r & 63;
        unsigned long long kw = kmask[w];
        int bit = (int)((kw >> b) & 1ull);
        unsigned long long lowmask = b ? ((1ull << b) - 1ull) : 0ull;
        int csum = (int)pref[w] + (int)__popcll(kw & lowmask) + bit;
        int kfin = (bit && csum <= TOPK) ? 1 : 0;
#pragma unroll
        for (int k = 0; k < 4; k++)
            boxes_o[((size_t)n * NBOX + r) * 4 + k] = bs[r * 4 + k];
        scores_o[n * NBOX + r] = ssort[r];
        keep_o[n * NBOX + r] = (float)kfin;
        ord_o[n * NBOX + r] = (float)ord[r];
    }
}

extern "C" void kernel_launch(void* const* d_in, const int* in_sizes, int n_in,
                              void* d_out, int out_size, void* d_ws, size_t ws_size,
                              hipStream_t stream) {
    const float* p2 = (const float*)d_in[0];
    const float* p3 = (const float*)d_in[1];
    const float* p4 = (const float*)d_in[2];
    const float* p5 = (const float*)d_in[3];
    const float* props = (const float*)d_in[4];
    const int* img = (const int*)d_in[5];
    const float* W1 = (const float*)d_in[6];
    const float* b1 = (const float*)d_in[7];
    const float* W2 = (const float*)d_in[8];
    const float* b2 = (const float*)d_in[9];
    const float* Wc = (const float*)d_in[10];
    const float* bc = (const float*)d_in[11];
    const float* Wb = (const float*)d_in[12];
    const float* bb = (const float*)d_in[13];

    float* X1 = (float*)d_ws;
    float* X2 = X1 + (size_t)2000 * FCD;
    float* SCf = X2 + (size_t)2000 * FCD;
    float* BXf = SCf + 2000;
    int* prep = (int*)(BXf + 8000);
    float* part = (float*)(prep + 2000 * 20);
    size_t used = (size_t)((char*)part - (char*)d_ws);
    size_t avail = ws_size > used ? ws_size - used : 0;

    prep_kernel<<<(NIMG * NBOX + 255) / 256, 256, 0, stream>>>(props, prep);

    int gmax = 0;
    const int cand[4] = {125, 63, 32, 16};
    for (int i = 0; i < 4; i++) {
        size_t need = (size_t)NPANEL * cand[i] * RB * FCD * sizeof(float);
        if (need <= avail) { gmax = cand[i]; break; }
    }

    if (gmax > 0) {
        for (int g0 = 0; g0 < NGROUP; g0 += gmax) {
            int gs = NGROUP - g0; if (gs > gmax) gs = gmax;
            dim3 gA(gs, NPANEL);
            fc1_panel<<<gA, 256, 0, stream>>>(p2, p3, p4, p5, prep, W1, part, g0, gs);
            int nelem = gs * RB * FCD;
            fold_bias_relu<<<(nelem + 255) / 256, 256, 0, stream>>>(part, b1, X1,
                                                                    g0 * RB, gs * RB, NPANEL);
        }
    } else {
        dim3 gfc(2, (NIMG * NBOX) / R1);
        fc1_fallback<<<gfc, 256, 0, stream>>>(p2, p3, p4, p5, prep, W1, b1, X1);
    }

    size_t need2 = (size_t)NP2 * NIMG * NBOX * FCD * sizeof(float);
    if (need2 <= avail) {
        dim3 g2(NIMG * NBOX / RB2, NP2);           // (250, 3)
        fc2_panel<<<g2, 256, 0, stream>>>(X1, W2, part);
        int nelem2 = NIMG * NBOX * FCD;
        fold_bias_relu<<<(nelem2 + 255) / 256, 256, 0, stream>>>(part, b2, X2,
                                                                 0, NIMG * NBOX, NP2);
    } else {
        dim3 gfc2(2, (NIMG * NBOX) / R1);
        fc2_seq<<<gfc2, 256, 0, stream>>>(X1, W2, b2, X2);
    }

    heads_par<<<NIMG * NBOX / HB, 256, 0, stream>>>(X2, Wc, bc, Wb, bb, props, img, SCf, BXf);

    size_t nms_lds = (size_t)NW * NBOX * 8 + NW * 8 + NW * 4
                   + (size_t)(NBOX + NBOX + NBOX * 4) * 4 + NBOX * 4;
    nms_bitmask<<<NIMG, 1024, nms_lds, stream>>>(SCf, BXf, (float*)d_out);
}